// Round 3
// baseline (449.330 us; speedup 1.0000x reference)
//
#include <hip/hip_runtime.h>
#include <stdint.h>
#include <math.h>

// ---------------------------------------------------------------------------
// MPCN (B=128, R=30, L=60, D=300, V=50000, P=3), f32 end-to-end.
// Round 3: chain matvecs -> batched tiled GEMMs (mean_kernel + 4 linear6
// launches). Review-level path kept bitwise-identical (selections frozen).
// ---------------------------------------------------------------------------

__host__ __device__ static inline void tf2x32(uint32_t k0, uint32_t k1,
                                              uint32_t x0, uint32_t x1,
                                              uint32_t* o0, uint32_t* o1) {
  uint32_t ks[3] = {k0, k1, k0 ^ k1 ^ 0x1BD11BDAu};
  x0 += ks[0]; x1 += ks[1];
  const int rotA[4] = {13, 15, 26, 6};
  const int rotB[4] = {17, 29, 16, 24};
#pragma unroll
  for (int i = 0; i < 5; ++i) {
    const int* rot = ((i & 1) == 0) ? rotA : rotB;
#pragma unroll
    for (int j = 0; j < 4; ++j) {
      x0 += x1;
      x1 = (x1 << rot[j]) | (x1 >> (32 - rot[j]));
      x1 ^= x0;
    }
    x0 += ks[(i + 1) % 3];
    x1 += ks[(i + 2) % 3] + (uint32_t)(i + 1);
  }
  *o0 = x0; *o1 = x1;
}

struct GKeys { uint32_t v[12]; };
struct Ptr6 {
  const float* X[6];
  const float* W[6];
  const float* Bb[6];
  float*       Y[6];
};

// JAX partitionable 32-bit draw: bits = o0 ^ o1 of threefry(key, (0, flat_idx))
__device__ static inline float jax_gumbel32(uint32_t k0, uint32_t k1, uint32_t idx) {
  uint32_t o0, o1;
  tf2x32(k0, k1, 0u, idx, &o0, &o1);
  uint32_t bits = o0 ^ o1;
  float f = __uint_as_float((bits >> 9) | 0x3f800000u) - 1.0f;
  float u = (f > 0.0f) ? f : 1.17549435e-38f;
  return -logf(-logf(u));
}

// K1: per-(side,b,r) sum of token embeddings over L -> S[(side*3840+row)*300+d]
__global__ __launch_bounds__(320)
void gather_sum_kernel(const int* __restrict__ uRevs, const int* __restrict__ iRevs,
                       const float* __restrict__ uEmb, const float* __restrict__ iEmb,
                       float* __restrict__ S) {
  int bid = blockIdx.x;
  int side = bid / 3840;
  int row = bid - side * 3840;
  const int* revs = side ? iRevs : uRevs;
  const float* emb = side ? iEmb : uEmb;
  __shared__ int toks[60];
  int t = threadIdx.x;
  if (t < 60) toks[t] = revs[row * 60 + t];
  __syncthreads();
  if (t < 300) {
    float acc = 0.f;
    for (int l = 0; l < 60; ++l)
      acc += emb[(size_t)toks[l] * 300 + t];
    S[(size_t)bid * 300 + t] = acc;
  }
}

// Fused review gate (bitwise-equal to two linears + combine).
__global__ __launch_bounds__(256)
void gate_fused_kernel(const float* __restrict__ X,
                       const float* __restrict__ W1, const float* __restrict__ b1,
                       const float* __restrict__ W2, const float* __restrict__ b2,
                       float* __restrict__ Y) {
  __shared__ __align__(16) float Xs[20][64];
  __shared__ __align__(16) float Ws1[20][64];
  __shared__ __align__(16) float Ws2[20][64];
  int t = threadIdx.x;
  int bm = blockIdx.x * 64;
  int n0 = blockIdx.y * 64;
  int tm4 = (t >> 4) * 4;
  int tn4 = (t & 15) * 4;
  float acc1[4][4] = {{0.f}};
  float acc2[4][4] = {{0.f}};
  int xm = t >> 2;
  int xk = (t & 3) * 5;
  for (int k0 = 0; k0 < 300; k0 += 20) {
    const float* xp = X + (size_t)(bm + xm) * 300 + k0 + xk;
#pragma unroll
    for (int j = 0; j < 5; ++j) Xs[xk + j][xm] = xp[j];
    {
      int dIdx = n0 + xm;
      bool ok = dIdx < 300;
      const float* wp1 = W1 + (size_t)dIdx * 300 + k0 + xk;
      const float* wp2 = W2 + (size_t)dIdx * 300 + k0 + xk;
#pragma unroll
      for (int j = 0; j < 5; ++j) Ws1[xk + j][xm] = ok ? wp1[j] : 0.f;
#pragma unroll
      for (int j = 0; j < 5; ++j) Ws2[xk + j][xm] = ok ? wp2[j] : 0.f;
    }
    __syncthreads();
#pragma unroll
    for (int kk = 0; kk < 20; ++kk) {
      const float4 a = *(const float4*)&Xs[kk][tm4];
      const float4 w1 = *(const float4*)&Ws1[kk][tn4];
      const float4 w2 = *(const float4*)&Ws2[kk][tn4];
      float av[4] = {a.x, a.y, a.z, a.w};
      float w1v[4] = {w1.x, w1.y, w1.z, w1.w};
      float w2v[4] = {w2.x, w2.y, w2.z, w2.w};
#pragma unroll
      for (int i = 0; i < 4; ++i)
#pragma unroll
        for (int j = 0; j < 4; ++j) {
          acc1[i][j] = fmaf(av[i], w1v[j], acc1[i][j]);
          acc2[i][j] = fmaf(av[i], w2v[j], acc2[i][j]);
        }
    }
    __syncthreads();
  }
#pragma unroll
  for (int i = 0; i < 4; ++i) {
    int row = bm + tm4 + i;
    float* yp = Y + (size_t)row * 300 + n0 + tn4;
#pragma unroll
    for (int j = 0; j < 4; ++j) {
      int col = n0 + tn4 + j;
      if (col < 300) {
        float a = acc1[i][j] + b1[col];
        float b = acc2[i][j] + b2[col];
        yp[j] = (1.f / (1.f + expf(-a))) * tanhf(b);
      }
    }
  }
}

// Tiled f32 linear with per-z pointer sets (z = blockIdx.z).
// TRANS: Y[n,d]=sum_k X[n,k]*W[d,k]; !TRANS: Y[n,e]=sum_k X[n,k]*W[k,e].
// Per-block arithmetic identical to round-1/2 linear_kernel.
template <bool TRANS, bool BIAS>
__global__ __launch_bounds__(256)
void linear6_kernel(Ptr6 P) {
  int z = blockIdx.z;
  const float* __restrict__ X = P.X[z];
  const float* __restrict__ W = P.W[z];
  const float* __restrict__ bias = P.Bb[z];
  float* __restrict__ Y = P.Y[z];
  __shared__ __align__(16) float Xs[20][64];
  __shared__ __align__(16) float Ws_[20][64];
  int t = threadIdx.x;
  int bm = blockIdx.x * 64;
  int n0 = blockIdx.y * 64;
  int tm4 = (t >> 4) * 4;
  int tn4 = (t & 15) * 4;
  float acc[4][4] = {{0.f}};
  int xm = t >> 2;
  int xk = (t & 3) * 5;
  for (int k0 = 0; k0 < 300; k0 += 20) {
    const float* xp = X + (size_t)(bm + xm) * 300 + k0 + xk;
#pragma unroll
    for (int j = 0; j < 5; ++j) Xs[xk + j][xm] = xp[j];
    if (TRANS) {
      int dIdx = n0 + xm;
      bool ok = dIdx < 300;
      const float* wp = W + (size_t)dIdx * 300 + k0 + xk;
#pragma unroll
      for (int j = 0; j < 5; ++j) Ws_[xk + j][xm] = ok ? wp[j] : 0.f;
    } else {
#pragma unroll
      for (int i = 0; i < 5; ++i) {
        int flat = t + i * 256;
        int kk = flat >> 6;
        int nn = flat & 63;
        int col = n0 + nn;
        Ws_[kk][nn] = (col < 300) ? W[(size_t)(k0 + kk) * 300 + col] : 0.f;
      }
    }
    __syncthreads();
#pragma unroll
    for (int kk = 0; kk < 20; ++kk) {
      const float4 a = *(const float4*)&Xs[kk][tm4];
      const float4 w = *(const float4*)&Ws_[kk][tn4];
      float av[4] = {a.x, a.y, a.z, a.w};
      float wv[4] = {w.x, w.y, w.z, w.w};
#pragma unroll
      for (int i = 0; i < 4; ++i)
#pragma unroll
        for (int j = 0; j < 4; ++j)
          acc[i][j] = fmaf(av[i], wv[j], acc[i][j]);
    }
    __syncthreads();
  }
  float bv[4] = {0.f, 0.f, 0.f, 0.f};
  if (BIAS) {
#pragma unroll
    for (int j = 0; j < 4; ++j) {
      int col = n0 + tn4 + j;
      if (col < 300) bv[j] = bias[col];
    }
  }
#pragma unroll
  for (int i = 0; i < 4; ++i) {
    int row = bm + tm4 + i;
    float* yp = Y + (size_t)row * 300 + n0 + tn4;
#pragma unroll
    for (int j = 0; j < 4; ++j) {
      int col = n0 + tn4 + j;
      if (col < 300) yp[j] = acc[i][j] + bv[j];
    }
  }
}

// Review-level scores + gumbel-argmax, batched over z=p. Bitwise round-1.
__global__ __launch_bounds__(256)
void review_argmax_kernel(const float* __restrict__ Tall, const float* __restrict__ Iall,
                          int* __restrict__ idxU, int* __restrict__ idxI, GKeys K) {
  int b = blockIdx.x, z = blockIdx.y, t = threadIdx.x;
  uint32_t ku0 = K.v[z * 4], ku1 = K.v[z * 4 + 1];
  uint32_t ki0 = K.v[z * 4 + 2], ki1 = K.v[z * 4 + 3];
  __shared__ float Is[9000];
  __shared__ float Sc[900];
  __shared__ float us[30], vs[30];
  const float* Tb = Tall + (size_t)z * 1152000 + (size_t)b * 9000;
  const float* Ib = Iall + (size_t)z * 1152000 + (size_t)b * 9000;
  for (int e = t; e < 9000; e += 256) Is[e] = Ib[e];
  __syncthreads();
  for (int id = t; id < 900; id += 256) {
    int r = id / 30, c = id - r * 30;
    const float* tr = Tb + r * 300;
    const float* ic = Is + c * 300;
    float acc = 0.f;
    for (int k = 0; k < 300; ++k) acc = fmaf(tr[k], ic[k], acc);
    Sc[id] = acc;
  }
  __syncthreads();
  if (t < 30) {
    float m = -3.4e38f;
    for (int c = 0; c < 30; ++c) m = fmaxf(m, Sc[t * 30 + c]);
    us[t] = m + jax_gumbel32(ku0, ku1, (uint32_t)(b * 30 + t));
  } else if (t >= 64 && t < 94) {
    int s = t - 64;
    float m = -3.4e38f;
    for (int r = 0; r < 30; ++r) m = fmaxf(m, Sc[r * 30 + s]);
    vs[s] = m + jax_gumbel32(ki0, ki1, (uint32_t)(b * 30 + s));
  }
  __syncthreads();
  if (t == 0) {
    int best = 0; float bvv = us[0];
    for (int r = 1; r < 30; ++r) { if (us[r] > bvv) { bvv = us[r]; best = r; } }
    idxU[z * 128 + b] = best;
  } else if (t == 1) {
    int best = 0; float bvv = vs[0];
    for (int s = 1; s < 30; ++s) { if (vs[s] > bvv) { bvv = vs[s]; best = s; } }
    idxI[z * 128 + b] = best;
  }
}

// Mean word embedding of the selected review. zz = p*2 + chain:
//   chain 0 -> item-side selected review (feeds user-score chain G)
//   chain 1 -> user-side selected review (feeds item-score chain H)
__global__ __launch_bounds__(320)
void mean_kernel(const int* __restrict__ uRevs, const int* __restrict__ iRevs,
                 const float* __restrict__ uEmb, const float* __restrict__ iEmb,
                 const int* __restrict__ idxU, const int* __restrict__ idxI,
                 float* __restrict__ MEAN) {
  int b = blockIdx.x, zz = blockIdx.y;
  int p = zz >> 1, chain = zz & 1;
  const int* revs = chain ? uRevs : iRevs;
  const float* emb = chain ? uEmb : iEmb;
  int idx = chain ? idxU[p * 128 + b] : idxI[p * 128 + b];
  __shared__ int toks[60];
  int t = threadIdx.x;
  if (t < 60) toks[t] = revs[(b * 30 + idx) * 60 + t];
  __syncthreads();
  if (t < 300) {
    float acc = 0.f;
    for (int l = 0; l < 60; ++l) acc += emb[(size_t)toks[l] * 300 + t];
    MEAN[((size_t)zz * 128 + b) * 300 + t] = acc * (1.f / 60.f);
  }
}

// Per (b, side, p): scores = selected-review word rows . gvec; softmax; weighted sum.
__global__ __launch_bounds__(256)
void word_rep_kernel(const int* __restrict__ uRevs, const int* __restrict__ iRevs,
                     const float* __restrict__ uEmb, const float* __restrict__ iEmb,
                     const int* __restrict__ idxU, const int* __restrict__ idxI,
                     const float* __restrict__ GH, float* __restrict__ JNT) {
  int b = blockIdx.x, side = blockIdx.y, p = blockIdx.z;
  const int* revs = side ? iRevs : uRevs;
  const float* emb = side ? iEmb : uEmb;
  int idx = side ? idxI[p * 128 + b] : idxU[p * 128 + b];
  const float* gv = GH + ((size_t)(p * 2 + side) * 128 + b) * 300;
  __shared__ int toks[60];
  __shared__ float g_s[300];
  __shared__ float score[60];
  __shared__ float probs[64];
  int t = threadIdx.x;
  if (t < 60) toks[t] = revs[(b * 30 + idx) * 60 + t];
  for (int d = t; d < 300; d += 256) g_s[d] = gv[d];
  __syncthreads();
  int w = t >> 6, j = t & 63;
  for (int i = 0; i < 15; ++i) {
    int l = w * 15 + i;
    const float* er = emb + (size_t)toks[l] * 300;
    float partial = 0.f;
#pragma unroll
    for (int c = 0; c < 5; ++c) {
      int k = j + c * 64;
      if (k < 300) partial = fmaf(er[k], g_s[k], partial);
    }
#pragma unroll
    for (int m = 32; m >= 1; m >>= 1) partial += __shfl_xor(partial, m);
    if (j == 0) score[l] = partial;
  }
  __syncthreads();
  if (w == 0) {
    float s = (j < 60) ? score[j] : -3.4e38f;
    float m = s;
#pragma unroll
    for (int mm = 32; mm >= 1; mm >>= 1) m = fmaxf(m, __shfl_xor(m, mm));
    float e = (j < 60) ? expf(s - m) : 0.f;
    float sum = e;
#pragma unroll
    for (int mm = 32; mm >= 1; mm >>= 1) sum += __shfl_xor(sum, mm);
    if (j < 60) probs[j] = e / sum;
  }
  __syncthreads();
  float* outp = JNT + (size_t)b * 1800 + side * 900 + p * 300;
  for (int d = t; d < 300; d += 256) {
    float acc = 0.f;
    for (int l = 0; l < 60; ++l)
      acc = fmaf(probs[l], emb[(size_t)toks[l] * 300 + d], acc);
    outp[d] = acc;
  }
}

// Factorization machine.
__global__ __launch_bounds__(64)
void fm_kernel(const float* __restrict__ JNT, const float* __restrict__ w0,
               const float* __restrict__ fw, const float* __restrict__ fv,
               float* __restrict__ out) {
  int b = blockIdx.x, lane = threadIdx.x;
  const float* x = JNT + (size_t)b * 1800;
  float lin = 0.f;
  float t1[10], t2[10];
#pragma unroll
  for (int k = 0; k < 10; ++k) { t1[k] = 0.f; t2[k] = 0.f; }
  for (int j = lane; j < 1800; j += 64) {
    float xv = x[j];
    lin = fmaf(fw[j], xv, lin);
    float xx = xv * xv;
#pragma unroll
    for (int k = 0; k < 10; ++k) {
      float v = fv[j * 10 + k];
      t1[k] = fmaf(xv, v, t1[k]);
      t2[k] = fmaf(xx, v * v, t2[k]);
    }
  }
#pragma unroll
  for (int m = 32; m >= 1; m >>= 1) {
    lin += __shfl_xor(lin, m);
#pragma unroll
    for (int k = 0; k < 10; ++k) {
      t1[k] += __shfl_xor(t1[k], m);
      t2[k] += __shfl_xor(t2[k], m);
    }
  }
  if (lane == 0) {
    float inter = 0.f;
#pragma unroll
    for (int k = 0; k < 10; ++k) inter += t1[k] * t1[k] - t2[k];
    out[b] = w0[0] + lin + 0.5f * inter;
  }
}

extern "C" void kernel_launch(void* const* d_in, const int* in_sizes, int n_in,
                              void* d_out, int out_size, void* d_ws, size_t ws_size,
                              hipStream_t stream) {
  (void)in_sizes; (void)n_in; (void)out_size;
  const int*   uRevs = (const int*)d_in[0];
  const int*   iRevs = (const int*)d_in[1];
  const float* uEmb  = (const float*)d_in[2];
  const float* iEmb  = (const float*)d_in[3];
  const float* g1w   = (const float*)d_in[4];
  const float* g1b   = (const float*)d_in[5];
  const float* g2w   = (const float*)d_in[6];
  const float* g2b   = (const float*)d_in[7];
  const float* Mr    = (const float*)d_in[8];
  const float* Wur   = (const float*)d_in[9];
  const float* bur   = (const float*)d_in[10];
  const float* Wir   = (const float*)d_in[11];
  const float* bir   = (const float*)d_in[12];
  const float* Mw    = (const float*)d_in[13];
  const float* Wuw   = (const float*)d_in[14];
  const float* buw   = (const float*)d_in[15];
  const float* Wiw   = (const float*)d_in[16];
  const float* biw   = (const float*)d_in[17];
  const float* fmw0  = (const float*)d_in[18];
  const float* fmw   = (const float*)d_in[19];
  const float* fmv   = (const float*)d_in[20];
  float* out = (float*)d_out;

  float* ws = (float*)d_ws;
  // Layout (floats):
  //   REV   @ 0          (2,304,000); TPall @ 0 (3,456,000) overlays after REV dead
  //   S     @ 3,456,000  (2,304,000); UPall @ 3,456,000 (3,456,000) overlays
  //   IPall @ 6,912,000  (3,456,000)
  //   GH    @ 10,368,000 (230,400)
  //   JNT   @ 10,598,400 (230,400)
  //   MEAN  @ 10,828,800 (230,400)
  //   T1    @ 11,059,200 (230,400)
  //   T2    @ 11,289,600 (230,400)
  //   idx   @ 11,520,000 (768 ints)
  const size_t NEED_BYTES = (size_t)11520768 * 4;
  if (ws_size < NEED_BYTES) return;

  float* REV   = ws + 0;
  float* TPall = ws + 0;
  float* S     = ws + 3456000;
  float* UPall = ws + 3456000;
  float* IPall = ws + 6912000;
  float* GH    = ws + 10368000;
  float* JNT   = ws + 10598400;
  float* MEAN  = ws + 10828800;
  float* T1    = ws + 11059200;
  float* T2    = ws + 11289600;
  int*   idxU  = (int*)(ws + 11520000);   // [3][128]
  int*   idxI  = idxU + 384;

  // Phase 1: gather-sum + fused review gate
  gather_sum_kernel<<<dim3(7680), dim3(320), 0, stream>>>(uRevs, iRevs, uEmb, iEmb, S);
  gate_fused_kernel<<<dim3(120, 5), 256, 0, stream>>>(S, g1w, g1b, g2w, g2b, REV);

  // Phase 2: review-level co-attention (UP+IP merged, z=6) + TP + argmax
  {
    Ptr6 P;
    for (int z = 0; z < 6; ++z) {
      int p = z % 3, side = z / 3;
      P.X[z] = REV + (size_t)side * 1152000;
      P.W[z] = (side ? Wir : Wur) + (size_t)p * 90000;
      P.Bb[z] = (side ? bir : bur) + p * 300;
      P.Y[z] = (side ? IPall : UPall) + (size_t)p * 1152000;
    }
    linear6_kernel<true, true><<<dim3(60, 5, 6), 256, 0, stream>>>(P);
    Ptr6 Q = {};
    for (int z = 0; z < 3; ++z) {
      Q.X[z] = UPall + (size_t)z * 1152000;
      Q.W[z] = Mr + (size_t)z * 90000;
      Q.Y[z] = TPall + (size_t)z * 1152000;
    }
    linear6_kernel<false, false><<<dim3(60, 5, 3), 256, 0, stream>>>(Q);
    GKeys K;
    for (int p = 0; p < 3; ++p) {
      tf2x32(0u, 42u, 0u, (uint32_t)(2 * p),     &K.v[p * 4],     &K.v[p * 4 + 1]);
      tf2x32(0u, 42u, 0u, (uint32_t)(2 * p + 1), &K.v[p * 4 + 2], &K.v[p * 4 + 3]);
    }
    review_argmax_kernel<<<dim3(128, 3), 256, 0, stream>>>(TPall, IPall, idxU, idxI, K);
  }

  // Phase 3: factorized word-level co-attention as batched GEMM chain
  mean_kernel<<<dim3(128, 6), 320, 0, stream>>>(
      uRevs, iRevs, uEmb, iEmb, idxU, idxI, MEAN);
  {
    // stage1 (TRANS+bias, z=6): T1[zz] = W1 @ MEAN[zz] + b1
    Ptr6 P;
    for (int zz = 0; zz < 6; ++zz) {
      int p = zz >> 1, chain = zz & 1;
      P.X[zz] = MEAN + (size_t)zz * 38400;
      P.W[zz] = (chain ? Wuw : Wiw) + (size_t)p * 90000;
      P.Bb[zz] = (chain ? buw : biw) + p * 300;
      P.Y[zz] = T1 + (size_t)zz * 38400;
    }
    linear6_kernel<true, true><<<dim3(2, 5, 6), 256, 0, stream>>>(P);
    // stage2 chain0 (TRANS, z=3): T2[2p] = Mw[p] @ T1[2p]
    Ptr6 Q = {};
    for (int z = 0; z < 3; ++z) {
      Q.X[z] = T1 + (size_t)(2 * z) * 38400;
      Q.W[z] = Mw + (size_t)z * 90000;
      Q.Y[z] = T2 + (size_t)(2 * z) * 38400;
    }
    linear6_kernel<true, false><<<dim3(2, 5, 3), 256, 0, stream>>>(Q);
    // stage2 chain1 (!TRANS, z=3): T2[2p+1] = T1[2p+1] @ Mw[p]
    Ptr6 R = {};
    for (int z = 0; z < 3; ++z) {
      R.X[z] = T1 + (size_t)(2 * z + 1) * 38400;
      R.W[z] = Mw + (size_t)z * 90000;
      R.Y[z] = T2 + (size_t)(2 * z + 1) * 38400;
    }
    linear6_kernel<false, false><<<dim3(2, 5, 3), 256, 0, stream>>>(R);
    // stage3 (!TRANS, z=6): GH[zz] = T2[zz] @ W3
    Ptr6 Sg;
    for (int zz = 0; zz < 6; ++zz) {
      int p = zz >> 1, chain = zz & 1;
      Sg.X[zz] = T2 + (size_t)zz * 38400;
      Sg.W[zz] = (chain ? Wiw : Wuw) + (size_t)p * 90000;
      Sg.Bb[zz] = nullptr;
      Sg.Y[zz] = GH + (size_t)zz * 38400;
    }
    linear6_kernel<false, false><<<dim3(2, 5, 6), 256, 0, stream>>>(Sg);
  }
  word_rep_kernel<<<dim3(128, 2, 3), 256, 0, stream>>>(
      uRevs, iRevs, uEmb, iEmb, idxU, idxI, GH, JNT);

  // Phase 4: factorization machine
  fm_kernel<<<dim3(128), 64, 0, stream>>>(JNT, fmw0, fmw, fmv, out);
}

// Round 4
// 438.550 us; speedup vs baseline: 1.0246x; 1.0246x over previous
//
#include <hip/hip_runtime.h>
#include <stdint.h>
#include <math.h>

// ---------------------------------------------------------------------------
// MPCN (B=128, R=30, L=60, D=300, V=50000, P=3), f32 end-to-end.
// Round 4: weight-algebra collapse (W' = Wur^T@Mr kills the TP GEMM;
// K_G = Wuw^T@Mw@Wiw kills the word chain), ILP-batched gathers,
// LDS padding [20][68], 13 -> 7 launches.
// Fallback note: if absmax ~1e-4, a review selection flipped -> revert W'.
// ---------------------------------------------------------------------------

__host__ __device__ static inline void tf2x32(uint32_t k0, uint32_t k1,
                                              uint32_t x0, uint32_t x1,
                                              uint32_t* o0, uint32_t* o1) {
  uint32_t ks[3] = {k0, k1, k0 ^ k1 ^ 0x1BD11BDAu};
  x0 += ks[0]; x1 += ks[1];
  const int rotA[4] = {13, 15, 26, 6};
  const int rotB[4] = {17, 29, 16, 24};
#pragma unroll
  for (int i = 0; i < 5; ++i) {
    const int* rot = ((i & 1) == 0) ? rotA : rotB;
#pragma unroll
    for (int j = 0; j < 4; ++j) {
      x0 += x1;
      x1 = (x1 << rot[j]) | (x1 >> (32 - rot[j]));
      x1 ^= x0;
    }
    x0 += ks[(i + 1) % 3];
    x1 += ks[(i + 2) % 3] + (uint32_t)(i + 1);
  }
  *o0 = x0; *o1 = x1;
}

struct GKeys { uint32_t v[12]; };
struct Ptr6 {
  const float* X[6];
  const float* W[6];
  const float* Bb[6];
  float*       Y[6];
};

__device__ static inline float jax_gumbel32(uint32_t k0, uint32_t k1, uint32_t idx) {
  uint32_t o0, o1;
  tf2x32(k0, k1, 0u, idx, &o0, &o1);
  uint32_t bits = o0 ^ o1;
  float f = __uint_as_float((bits >> 9) | 0x3f800000u) - 1.0f;
  float u = (f > 0.0f) ? f : 1.17549435e-38f;
  return -logf(-logf(u));
}

#define MODE_NN 0
#define MODE_NT 1
#define MODE_TN 2

// Generic 64x64 f32 GEMM tile, K=N=300, ld=300. Works in blocks of >=256
// threads (threads >=256 idle but hit barriers). Optional transposed
// second output Yt (for K_G^T). Row clamp makes OOB X rows safe.
template <int MODE, bool BIAS>
__device__ __forceinline__ void gemm_tile(const float* __restrict__ X,
                                          const float* __restrict__ W,
                                          const float* __restrict__ bias,
                                          float* __restrict__ Y,
                                          float* __restrict__ Yt,
                                          int M, int bm, int n0, int t) {
  __shared__ __align__(16) float Xs[20][68];
  __shared__ __align__(16) float Ws_[20][68];
  const bool act = t < 256;
  int tm4 = ((t >> 4) & 15) * 4;
  int tn4 = (t & 15) * 4;
  float acc[4][4] = {{0.f}};
  int xm = t >> 2;
  int xk = (t & 3) * 5;
  for (int k0 = 0; k0 < 300; k0 += 20) {
    if (act) {
      if (MODE == MODE_TN) {
#pragma unroll
        for (int i = 0; i < 5; ++i) {
          int flat = t + i * 256;
          int kk = flat >> 6, nn = flat & 63;
          int r = bm + nn;
          Xs[kk][nn] = (r < 300) ? X[(size_t)(k0 + kk) * 300 + r] : 0.f;
        }
      } else {
        int rr = bm + xm; if (rr >= M) rr = M - 1;
        const float* xp = X + (size_t)rr * 300 + k0 + xk;
#pragma unroll
        for (int j = 0; j < 5; ++j) Xs[xk + j][xm] = xp[j];
      }
      if (MODE == MODE_NT) {
        int d = n0 + xm;
        bool ok = d < 300;
        const float* wp = W + (size_t)d * 300 + k0 + xk;
#pragma unroll
        for (int j = 0; j < 5; ++j) Ws_[xk + j][xm] = ok ? wp[j] : 0.f;
      } else {
#pragma unroll
        for (int i = 0; i < 5; ++i) {
          int flat = t + i * 256;
          int kk = flat >> 6, nn = flat & 63;
          int col = n0 + nn;
          Ws_[kk][nn] = (col < 300) ? W[(size_t)(k0 + kk) * 300 + col] : 0.f;
        }
      }
    }
    __syncthreads();
    if (act) {
#pragma unroll
      for (int kk = 0; kk < 20; ++kk) {
        const float4 a = *(const float4*)&Xs[kk][tm4];
        const float4 w = *(const float4*)&Ws_[kk][tn4];
        float av[4] = {a.x, a.y, a.z, a.w};
        float wv[4] = {w.x, w.y, w.z, w.w};
#pragma unroll
        for (int i = 0; i < 4; ++i)
#pragma unroll
          for (int j = 0; j < 4; ++j)
            acc[i][j] = fmaf(av[i], wv[j], acc[i][j]);
      }
    }
    __syncthreads();
  }
  if (!act) return;
  float bv[4] = {0.f, 0.f, 0.f, 0.f};
  if (BIAS) {
#pragma unroll
    for (int j = 0; j < 4; ++j) {
      int col = n0 + tn4 + j;
      if (col < 300) bv[j] = bias[col];
    }
  }
#pragma unroll
  for (int i = 0; i < 4; ++i) {
    int row = bm + tm4 + i;
    if (row < M) {
      float* yp = Y + (size_t)row * 300 + n0 + tn4;
#pragma unroll
      for (int j = 0; j < 4; ++j) {
        int col = n0 + tn4 + j;
        if (col < 300) yp[j] = acc[i][j] + bv[j];
      }
    }
  }
  if (Yt) {
#pragma unroll
    for (int i = 0; i < 4; ++i) {
      int row = bm + tm4 + i;
      if (row < M) {
#pragma unroll
        for (int j = 0; j < 4; ++j) {
          int col = n0 + tn4 + j;
          if (col < 300) Yt[(size_t)col * 300 + row] = acc[i][j];
        }
      }
    }
  }
}

// L1 prep: gather-sum (blocks 0..7679, ILP-batched loads w/ sequential adds),
// W' = Wur^T @ Mr (75), A1 = Mw @ Wiw (75), WirT transpose (3).
__global__ __launch_bounds__(320)
void prep_kernel(const int* __restrict__ uRevs, const int* __restrict__ iRevs,
                 const float* __restrict__ uEmb, const float* __restrict__ iEmb,
                 const float* __restrict__ Wur, const float* __restrict__ Mr,
                 const float* __restrict__ Mw, const float* __restrict__ Wiw,
                 const float* __restrict__ Wir,
                 float* __restrict__ S, float* __restrict__ Wp,
                 float* __restrict__ A1, float* __restrict__ WirT) {
  int bid = blockIdx.x, t = threadIdx.x;
  if (bid < 7680) {
    int side = bid / 3840;
    int row = bid - side * 3840;
    const int* revs = side ? iRevs : uRevs;
    const float* emb = side ? iEmb : uEmb;
    __shared__ int toks[60];
    if (t < 60) toks[t] = revs[row * 60 + t];
    __syncthreads();
    if (t < 300) {
      float acc = 0.f;
      for (int l0 = 0; l0 < 60; l0 += 6) {
        float v0 = emb[(size_t)toks[l0 + 0] * 300 + t];
        float v1 = emb[(size_t)toks[l0 + 1] * 300 + t];
        float v2 = emb[(size_t)toks[l0 + 2] * 300 + t];
        float v3 = emb[(size_t)toks[l0 + 3] * 300 + t];
        float v4 = emb[(size_t)toks[l0 + 4] * 300 + t];
        float v5 = emb[(size_t)toks[l0 + 5] * 300 + t];
        acc += v0; acc += v1; acc += v2; acc += v3; acc += v4; acc += v5;
      }
      S[(size_t)bid * 300 + t] = acc;
    }
  } else if (bid < 7755) {
    int zi = bid - 7680, z = zi / 25, r = zi % 25;
    gemm_tile<MODE_TN, false>(Wur + (size_t)z * 90000, Mr + (size_t)z * 90000,
                              nullptr, Wp + (size_t)z * 90000, nullptr,
                              300, (r / 5) * 64, (r % 5) * 64, t);
  } else if (bid < 7830) {
    int zi = bid - 7755, z = zi / 25, r = zi % 25;
    gemm_tile<MODE_NN, false>(Mw + (size_t)z * 90000, Wiw + (size_t)z * 90000,
                              nullptr, A1 + (size_t)z * 90000, nullptr,
                              300, (r / 5) * 64, (r % 5) * 64, t);
  } else {
    int z = bid - 7830;
    const float* src = Wir + (size_t)z * 90000;
    float* dst = WirT + (size_t)z * 90000;
    for (int e = t; e < 90000; e += 320)
      dst[(size_t)(e % 300) * 300 + e / 300] = src[e];
  }
}

// L2 gate: fused review gate (600 blocks, bitwise-identical arithmetic),
// K_G = Wuw^T @ A1 with transposed copy (75), bias chains (3).
__global__ __launch_bounds__(256)
void gate_kernel(const float* __restrict__ S,
                 const float* __restrict__ g1w, const float* __restrict__ g1b,
                 const float* __restrict__ g2w, const float* __restrict__ g2b,
                 float* __restrict__ REV,
                 const float* __restrict__ Wuw, const float* __restrict__ buw,
                 const float* __restrict__ Wiw, const float* __restrict__ biw,
                 const float* __restrict__ Mw, const float* __restrict__ Mr,
                 const float* __restrict__ bur,
                 const float* __restrict__ A1, float* __restrict__ KG,
                 float* __restrict__ KGT, float* __restrict__ CGH,
                 float* __restrict__ Bp) {
  int bid = blockIdx.x, t = threadIdx.x;
  if (bid < 600) {
    __shared__ __align__(16) float Xs[20][68];
    __shared__ __align__(16) float Ws1[20][68];
    __shared__ __align__(16) float Ws2[20][68];
    int bm = (bid / 5) * 64;
    int n0 = (bid % 5) * 64;
    int tm4 = (t >> 4) * 4;
    int tn4 = (t & 15) * 4;
    float acc1[4][4] = {{0.f}};
    float acc2[4][4] = {{0.f}};
    int xm = t >> 2;
    int xk = (t & 3) * 5;
    for (int k0 = 0; k0 < 300; k0 += 20) {
      const float* xp = S + (size_t)(bm + xm) * 300 + k0 + xk;
#pragma unroll
      for (int j = 0; j < 5; ++j) Xs[xk + j][xm] = xp[j];
      {
        int dIdx = n0 + xm;
        bool ok = dIdx < 300;
        const float* wp1 = g1w + (size_t)dIdx * 300 + k0 + xk;
        const float* wp2 = g2w + (size_t)dIdx * 300 + k0 + xk;
#pragma unroll
        for (int j = 0; j < 5; ++j) Ws1[xk + j][xm] = ok ? wp1[j] : 0.f;
#pragma unroll
        for (int j = 0; j < 5; ++j) Ws2[xk + j][xm] = ok ? wp2[j] : 0.f;
      }
      __syncthreads();
#pragma unroll
      for (int kk = 0; kk < 20; ++kk) {
        const float4 a = *(const float4*)&Xs[kk][tm4];
        const float4 w1 = *(const float4*)&Ws1[kk][tn4];
        const float4 w2 = *(const float4*)&Ws2[kk][tn4];
        float av[4] = {a.x, a.y, a.z, a.w};
        float w1v[4] = {w1.x, w1.y, w1.z, w1.w};
        float w2v[4] = {w2.x, w2.y, w2.z, w2.w};
#pragma unroll
        for (int i = 0; i < 4; ++i)
#pragma unroll
          for (int j = 0; j < 4; ++j) {
            acc1[i][j] = fmaf(av[i], w1v[j], acc1[i][j]);
            acc2[i][j] = fmaf(av[i], w2v[j], acc2[i][j]);
          }
      }
      __syncthreads();
    }
#pragma unroll
    for (int i = 0; i < 4; ++i) {
      int row = bm + tm4 + i;
      float* yp = REV + (size_t)row * 300 + n0 + tn4;
#pragma unroll
      for (int j = 0; j < 4; ++j) {
        int col = n0 + tn4 + j;
        if (col < 300) {
          float a = acc1[i][j] + g1b[col];
          float b = acc2[i][j] + g2b[col];
          yp[j] = (1.f / (1.f + expf(-a))) * tanhf(b);
        }
      }
    }
  } else if (bid < 675) {
    int zi = bid - 600, z = zi / 25, r = zi % 25;
    gemm_tile<MODE_TN, false>(Wuw + (size_t)z * 90000, A1 + (size_t)z * 90000,
                              nullptr, KG + (size_t)z * 90000,
                              KGT + (size_t)z * 90000,
                              300, (r / 5) * 64, (r % 5) * 64, t);
  } else {
    // bias chains: c_g = Wuw^T(Mw biw), c_h = Wiw^T(Mw^T buw), b' = Mr^T bur
    int z = bid - 675;
    __shared__ float vb[300], t1s[300], t2s[300];
    const float* Mwz = Mw + (size_t)z * 90000;
    const float* Wuwz = Wuw + (size_t)z * 90000;
    const float* Wiwz = Wiw + (size_t)z * 90000;
    const float* Mrz = Mr + (size_t)z * 90000;
    for (int k = t; k < 300; k += 256) vb[k] = biw[z * 300 + k];
    __syncthreads();
    for (int e = t; e < 300; e += 256) {
      float a = 0.f;
      for (int k = 0; k < 300; ++k) a = fmaf(Mwz[(size_t)e * 300 + k], vb[k], a);
      t1s[e] = a;
    }
    __syncthreads();
    for (int k = t; k < 300; k += 256) {
      float a = 0.f;
      for (int d = 0; d < 300; ++d) a = fmaf(Wuwz[(size_t)d * 300 + k], t1s[d], a);
      CGH[(size_t)(2 * z) * 300 + k] = a;
    }
    __syncthreads();
    for (int d = t; d < 300; d += 256) vb[d] = buw[z * 300 + d];
    __syncthreads();
    for (int e = t; e < 300; e += 256) {
      float a = 0.f;
      for (int d = 0; d < 300; ++d) a = fmaf(Mwz[(size_t)d * 300 + e], vb[d], a);
      t2s[e] = a;
    }
    __syncthreads();
    for (int k = t; k < 300; k += 256) {
      float a = 0.f;
      for (int e = 0; e < 300; ++e) a = fmaf(Wiwz[(size_t)e * 300 + k], t2s[e], a);
      CGH[(size_t)(2 * z + 1) * 300 + k] = a;
    }
    __syncthreads();
    for (int d = t; d < 300; d += 256) vb[d] = bur[z * 300 + d];
    __syncthreads();
    for (int e = t; e < 300; e += 256) {
      float a = 0.f;
      for (int d = 0; d < 300; ++d) a = fmaf(Mrz[(size_t)d * 300 + e], vb[d], a);
      Bp[z * 300 + e] = a;
    }
  }
}

// L3/L5: batched NN GEMM with per-z pointer sets.
template <bool BIAS>
__global__ __launch_bounds__(256)
void nn6_kernel(Ptr6 P, int M) {
  int z = blockIdx.z;
  gemm_tile<MODE_NN, BIAS>(P.X[z], P.W[z], P.Bb[z], P.Y[z], nullptr,
                           M, blockIdx.x * 64, blockIdx.y * 64, threadIdx.x);
}

// L4: review scores + gumbel-argmax (bitwise round-1 math) + fused MEAN.
__global__ __launch_bounds__(256)
void argmax_mean_kernel(const float* __restrict__ Tall, const float* __restrict__ Iall,
                        const int* __restrict__ uRevs, const int* __restrict__ iRevs,
                        const float* __restrict__ uEmb, const float* __restrict__ iEmb,
                        int* __restrict__ idxU, int* __restrict__ idxI,
                        float* __restrict__ MEAN, GKeys K) {
  int b = blockIdx.x, z = blockIdx.y, t = threadIdx.x;
  uint32_t ku0 = K.v[z * 4], ku1 = K.v[z * 4 + 1];
  uint32_t ki0 = K.v[z * 4 + 2], ki1 = K.v[z * 4 + 3];
  __shared__ float Is[30 * 301];
  __shared__ float Sc[900];
  __shared__ float us[30], vs[30];
  __shared__ int selU, selI;
  __shared__ int toksI_s[60], toksU_s[60];
  const float* Tb = Tall + (size_t)z * 1152000 + (size_t)b * 9000;
  const float* Ib = Iall + (size_t)z * 1152000 + (size_t)b * 9000;
  for (int e = t; e < 9000; e += 256) Is[(e / 300) * 301 + (e % 300)] = Ib[e];
  __syncthreads();
  for (int id = t; id < 900; id += 256) {
    int r = id / 30, c = id - r * 30;
    const float* tr = Tb + r * 300;
    const float* ic = Is + c * 301;
    float acc = 0.f;
    for (int k = 0; k < 300; ++k) acc = fmaf(tr[k], ic[k], acc);
    Sc[id] = acc;
  }
  __syncthreads();
  if (t < 30) {
    float m = -3.4e38f;
    for (int c = 0; c < 30; ++c) m = fmaxf(m, Sc[t * 30 + c]);
    us[t] = m + jax_gumbel32(ku0, ku1, (uint32_t)(b * 30 + t));
  } else if (t >= 64 && t < 94) {
    int s = t - 64;
    float m = -3.4e38f;
    for (int r = 0; r < 30; ++r) m = fmaxf(m, Sc[r * 30 + s]);
    vs[s] = m + jax_gumbel32(ki0, ki1, (uint32_t)(b * 30 + s));
  }
  __syncthreads();
  if (t == 0) {
    int best = 0; float bvv = us[0];
    for (int r = 1; r < 30; ++r) { if (us[r] > bvv) { bvv = us[r]; best = r; } }
    idxU[z * 128 + b] = best; selU = best;
  } else if (t == 1) {
    int best = 0; float bvv = vs[0];
    for (int s = 1; s < 30; ++s) { if (vs[s] > bvv) { bvv = vs[s]; best = s; } }
    idxI[z * 128 + b] = best; selI = best;
  }
  __syncthreads();
  if (t < 60) toksI_s[t] = iRevs[(b * 30 + selI) * 60 + t];
  else if (t >= 64 && t < 124) toksU_s[t - 64] = uRevs[(b * 30 + selU) * 60 + (t - 64)];
  __syncthreads();
  // MEAN[2z] = item-selected mean (feeds G), MEAN[2z+1] = user-selected mean.
  for (int dd = t; dd < 600; dd += 256) {
    int side = dd / 300;
    int d = dd - side * 300;
    const int* tk = side ? toksU_s : toksI_s;
    const float* em = side ? uEmb : iEmb;
    float acc = 0.f;
    for (int l0 = 0; l0 < 60; l0 += 6) {
      float v0 = em[(size_t)tk[l0 + 0] * 300 + d];
      float v1 = em[(size_t)tk[l0 + 1] * 300 + d];
      float v2 = em[(size_t)tk[l0 + 2] * 300 + d];
      float v3 = em[(size_t)tk[l0 + 3] * 300 + d];
      float v4 = em[(size_t)tk[l0 + 4] * 300 + d];
      float v5 = em[(size_t)tk[l0 + 5] * 300 + d];
      acc += v0; acc += v1; acc += v2; acc += v3; acc += v4; acc += v5;
    }
    MEAN[((size_t)(2 * z + side) * 128 + b) * 300 + d] = acc * (1.f / 60.f);
  }
}

// L6: per (b, side, p): scores = word rows . gvec; softmax; weighted sum.
__global__ __launch_bounds__(256)
void word_rep_kernel(const int* __restrict__ uRevs, const int* __restrict__ iRevs,
                     const float* __restrict__ uEmb, const float* __restrict__ iEmb,
                     const int* __restrict__ idxU, const int* __restrict__ idxI,
                     const float* __restrict__ GH, float* __restrict__ JNT) {
  int b = blockIdx.x, side = blockIdx.y, p = blockIdx.z;
  const int* revs = side ? iRevs : uRevs;
  const float* emb = side ? iEmb : uEmb;
  int idx = side ? idxI[p * 128 + b] : idxU[p * 128 + b];
  const float* gv = GH + ((size_t)(p * 2 + side) * 128 + b) * 300;
  __shared__ int toks[60];
  __shared__ float g_s[300];
  __shared__ float score[60];
  __shared__ float probs[64];
  int t = threadIdx.x;
  if (t < 60) toks[t] = revs[(b * 30 + idx) * 60 + t];
  for (int d = t; d < 300; d += 256) g_s[d] = gv[d];
  __syncthreads();
  int w = t >> 6, j = t & 63;
  for (int i = 0; i < 15; ++i) {
    int l = w * 15 + i;
    const float* er = emb + (size_t)toks[l] * 300;
    float partial = 0.f;
#pragma unroll
    for (int c = 0; c < 5; ++c) {
      int k = j + c * 64;
      if (k < 300) partial = fmaf(er[k], g_s[k], partial);
    }
#pragma unroll
    for (int m = 32; m >= 1; m >>= 1) partial += __shfl_xor(partial, m);
    if (j == 0) score[l] = partial;
  }
  __syncthreads();
  if (w == 0) {
    float s = (j < 60) ? score[j] : -3.4e38f;
    float m = s;
#pragma unroll
    for (int mm = 32; mm >= 1; mm >>= 1) m = fmaxf(m, __shfl_xor(m, mm));
    float e = (j < 60) ? expf(s - m) : 0.f;
    float sum = e;
#pragma unroll
    for (int mm = 32; mm >= 1; mm >>= 1) sum += __shfl_xor(sum, mm);
    if (j < 60) probs[j] = e / sum;
  }
  __syncthreads();
  float* outp = JNT + (size_t)b * 1800 + side * 900 + p * 300;
  for (int d = t; d < 300; d += 256) {
    float acc = 0.f;
    for (int l0 = 0; l0 < 60; l0 += 6) {
      float e0 = emb[(size_t)toks[l0 + 0] * 300 + d];
      float e1 = emb[(size_t)toks[l0 + 1] * 300 + d];
      float e2 = emb[(size_t)toks[l0 + 2] * 300 + d];
      float e3 = emb[(size_t)toks[l0 + 3] * 300 + d];
      float e4 = emb[(size_t)toks[l0 + 4] * 300 + d];
      float e5 = emb[(size_t)toks[l0 + 5] * 300 + d];
      acc = fmaf(probs[l0 + 0], e0, acc);
      acc = fmaf(probs[l0 + 1], e1, acc);
      acc = fmaf(probs[l0 + 2], e2, acc);
      acc = fmaf(probs[l0 + 3], e3, acc);
      acc = fmaf(probs[l0 + 4], e4, acc);
      acc = fmaf(probs[l0 + 5], e5, acc);
    }
    outp[d] = acc;
  }
}

// L7: factorization machine.
__global__ __launch_bounds__(64)
void fm_kernel(const float* __restrict__ JNT, const float* __restrict__ w0,
               const float* __restrict__ fw, const float* __restrict__ fv,
               float* __restrict__ out) {
  int b = blockIdx.x, lane = threadIdx.x;
  const float* x = JNT + (size_t)b * 1800;
  float lin = 0.f;
  float t1[10], t2[10];
#pragma unroll
  for (int k = 0; k < 10; ++k) { t1[k] = 0.f; t2[k] = 0.f; }
  for (int j = lane; j < 1800; j += 64) {
    float xv = x[j];
    lin = fmaf(fw[j], xv, lin);
    float xx = xv * xv;
#pragma unroll
    for (int k = 0; k < 10; ++k) {
      float v = fv[j * 10 + k];
      t1[k] = fmaf(xv, v, t1[k]);
      t2[k] = fmaf(xx, v * v, t2[k]);
    }
  }
#pragma unroll
  for (int m = 32; m >= 1; m >>= 1) {
    lin += __shfl_xor(lin, m);
#pragma unroll
    for (int k = 0; k < 10; ++k) {
      t1[k] += __shfl_xor(t1[k], m);
      t2[k] += __shfl_xor(t2[k], m);
    }
  }
  if (lane == 0) {
    float inter = 0.f;
#pragma unroll
    for (int k = 0; k < 10; ++k) inter += t1[k] * t1[k] - t2[k];
    out[b] = w0[0] + lin + 0.5f * inter;
  }
}

extern "C" void kernel_launch(void* const* d_in, const int* in_sizes, int n_in,
                              void* d_out, int out_size, void* d_ws, size_t ws_size,
                              hipStream_t stream) {
  (void)in_sizes; (void)n_in; (void)out_size;
  const int*   uRevs = (const int*)d_in[0];
  const int*   iRevs = (const int*)d_in[1];
  const float* uEmb  = (const float*)d_in[2];
  const float* iEmb  = (const float*)d_in[3];
  const float* g1w   = (const float*)d_in[4];
  const float* g1b   = (const float*)d_in[5];
  const float* g2w   = (const float*)d_in[6];
  const float* g2b   = (const float*)d_in[7];
  const float* Mr    = (const float*)d_in[8];
  const float* Wur   = (const float*)d_in[9];
  const float* bur   = (const float*)d_in[10];
  const float* Wir   = (const float*)d_in[11];
  const float* bir   = (const float*)d_in[12];
  const float* Mw    = (const float*)d_in[13];
  const float* Wuw   = (const float*)d_in[14];
  const float* buw   = (const float*)d_in[15];
  const float* Wiw   = (const float*)d_in[16];
  const float* biw   = (const float*)d_in[17];
  const float* fmw0  = (const float*)d_in[18];
  const float* fmw   = (const float*)d_in[19];
  const float* fmv   = (const float*)d_in[20];
  float* out = (float*)d_out;

  float* ws = (float*)d_ws;
  // Layout (floats), with lifetime overlays:
  //   S     @ 0          (2,304,000)  L1..L2 ; TPall @ 0 (3,456,000) L3..L4
  //   REV   @ 3,456,000  (2,304,000)  L2..L3
  //     MEAN @ 3,456,000 (230,400) L4.. ; GH @ 3,686,400 L5.. ;
  //     JNT @ 3,916,800 L6.. ; idx @ 4,147,200 (768 int) L4..
  //   IPall @ 5,760,000  (3,456,000)  L3..L4
  //   A1 @ 9,216,000 ; Wp @ 9,486,000 ; WirT @ 9,756,000 ;
  //   KG @ 10,026,000 ; KGT @ 10,296,000 ; Bp @ 10,566,000 ; CGH @ 10,567,024
  const size_t NEED_BYTES = (size_t)10568824 * 4;
  if (ws_size < NEED_BYTES) return;

  float* S     = ws + 0;
  float* TPall = ws + 0;
  float* REV   = ws + 3456000;
  float* MEAN  = ws + 3456000;
  float* GH    = ws + 3686400;
  float* JNT   = ws + 3916800;
  int*   idxU  = (int*)(ws + 4147200);
  int*   idxI  = idxU + 384;
  float* IPall = ws + 5760000;
  float* A1    = ws + 9216000;
  float* Wp    = ws + 9486000;
  float* WirT  = ws + 9756000;
  float* KG    = ws + 10026000;
  float* KGT   = ws + 10296000;
  float* Bp    = ws + 10566000;
  float* CGH   = ws + 10567024;

  // L1: gather-sum + weight precomputes
  prep_kernel<<<dim3(7833), dim3(320), 0, stream>>>(
      uRevs, iRevs, uEmb, iEmb, Wur, Mr, Mw, Wiw, Wir, S, Wp, A1, WirT);

  // L2: review gate + K_G (+transpose) + bias chains
  gate_kernel<<<dim3(678), dim3(256), 0, stream>>>(
      S, g1w, g1b, g2w, g2b, REV, Wuw, buw, Wiw, biw, Mw, Mr, bur,
      A1, KG, KGT, CGH, Bp);

  // L3: TP = REV_u @ W' + b' ; IP = REV_i @ WirT + bir   (all NN, z=6)
  {
    Ptr6 P;
    for (int z = 0; z < 3; ++z) {
      P.X[z] = REV;
      P.W[z] = Wp + (size_t)z * 90000;
      P.Bb[z] = Bp + z * 300;
      P.Y[z] = TPall + (size_t)z * 1152000;
      P.X[z + 3] = REV + (size_t)3840 * 300;
      P.W[z + 3] = WirT + (size_t)z * 90000;
      P.Bb[z + 3] = bir + z * 300;
      P.Y[z + 3] = IPall + (size_t)z * 1152000;
    }
    nn6_kernel<true><<<dim3(60, 5, 6), 256, 0, stream>>>(P, 3840);
  }

  // L4: gumbel-argmax + fused MEAN
  {
    GKeys K;
    for (int p = 0; p < 3; ++p) {
      tf2x32(0u, 42u, 0u, (uint32_t)(2 * p),     &K.v[p * 4],     &K.v[p * 4 + 1]);
      tf2x32(0u, 42u, 0u, (uint32_t)(2 * p + 1), &K.v[p * 4 + 2], &K.v[p * 4 + 3]);
    }
    argmax_mean_kernel<<<dim3(128, 3), 256, 0, stream>>>(
        TPall, IPall, uRevs, iRevs, uEmb, iEmb, idxU, idxI, MEAN, K);
  }

  // L5: GH[2p] = MEAN_i @ K_G^T + c_g ; GH[2p+1] = MEAN_u @ K_G + c_h
  {
    Ptr6 P;
    for (int zz = 0; zz < 6; ++zz) {
      int p = zz >> 1;
      P.X[zz] = MEAN + (size_t)zz * 38400;
      P.W[zz] = (zz & 1) ? KG + (size_t)p * 90000 : KGT + (size_t)p * 90000;
      P.Bb[zz] = CGH + (size_t)zz * 300;
      P.Y[zz] = GH + (size_t)zz * 38400;
    }
    nn6_kernel<true><<<dim3(2, 5, 6), 256, 0, stream>>>(P, 128);
  }

  // L6: word-level softmax representations
  word_rep_kernel<<<dim3(128, 2, 3), 256, 0, stream>>>(
      uRevs, iRevs, uEmb, iEmb, idxU, idxI, GH, JNT);

  // L7: factorization machine
  fm_kernel<<<dim3(128), 64, 0, stream>>>(JNT, fmw0, fmw, fmv, out);
}

// Round 5
// 432.821 us; speedup vs baseline: 1.0381x; 1.0132x over previous
//
#include <hip/hip_runtime.h>
#include <stdint.h>
#include <math.h>

// ---------------------------------------------------------------------------
// MPCN (B=128, R=30, L=60, D=300, V=50000, P=3), f32 end-to-end.
// Round 5: un-fuse gather from big-LDS GEMMs (restore occupancy), 10-deep
// ILP gather, 128x64/8x4 rev GEMM (fewer ds_read_b128 per FMA).
// Selection-critical values (S, REV, TP, IP, gumbel) bitwise-stable vs r4.
// ---------------------------------------------------------------------------

__host__ __device__ static inline void tf2x32(uint32_t k0, uint32_t k1,
                                              uint32_t x0, uint32_t x1,
                                              uint32_t* o0, uint32_t* o1) {
  uint32_t ks[3] = {k0, k1, k0 ^ k1 ^ 0x1BD11BDAu};
  x0 += ks[0]; x1 += ks[1];
  const int rotA[4] = {13, 15, 26, 6};
  const int rotB[4] = {17, 29, 16, 24};
#pragma unroll
  for (int i = 0; i < 5; ++i) {
    const int* rot = ((i & 1) == 0) ? rotA : rotB;
#pragma unroll
    for (int j = 0; j < 4; ++j) {
      x0 += x1;
      x1 = (x1 << rot[j]) | (x1 >> (32 - rot[j]));
      x1 ^= x0;
    }
    x0 += ks[(i + 1) % 3];
    x1 += ks[(i + 2) % 3] + (uint32_t)(i + 1);
  }
  *o0 = x0; *o1 = x1;
}

struct GKeys { uint32_t v[12]; };
struct Ptr6 {
  const float* X[6];
  const float* W[6];
  const float* Bb[6];
  float*       Y[6];
};

__device__ static inline float jax_gumbel32(uint32_t k0, uint32_t k1, uint32_t idx) {
  uint32_t o0, o1;
  tf2x32(k0, k1, 0u, idx, &o0, &o1);
  uint32_t bits = o0 ^ o1;
  float f = __uint_as_float((bits >> 9) | 0x3f800000u) - 1.0f;
  float u = (f > 0.0f) ? f : 1.17549435e-38f;
  return -logf(-logf(u));
}

#define MODE_NN 0
#define MODE_NT 1
#define MODE_TN 2

// 64x64 f32 GEMM tile, K=N=300, ld=300. Blocks >=256 threads (extras idle
// but reach barriers). Optional transposed second output Yt.
template <int MODE, bool BIAS>
__device__ __forceinline__ void gemm_tile(const float* __restrict__ X,
                                          const float* __restrict__ W,
                                          const float* __restrict__ bias,
                                          float* __restrict__ Y,
                                          float* __restrict__ Yt,
                                          int M, int bm, int n0, int t) {
  __shared__ __align__(16) float Xs[20][68];
  __shared__ __align__(16) float Ws_[20][68];
  const bool act = t < 256;
  int tm4 = ((t >> 4) & 15) * 4;
  int tn4 = (t & 15) * 4;
  float acc[4][4] = {{0.f}};
  int xm = t >> 2;
  int xk = (t & 3) * 5;
  for (int k0 = 0; k0 < 300; k0 += 20) {
    if (act) {
      if (MODE == MODE_TN) {
#pragma unroll
        for (int i = 0; i < 5; ++i) {
          int flat = t + i * 256;
          int kk = flat >> 6, nn = flat & 63;
          int r = bm + nn;
          Xs[kk][nn] = (r < 300) ? X[(size_t)(k0 + kk) * 300 + r] : 0.f;
        }
      } else {
        int rr = bm + xm; if (rr >= M) rr = M - 1;
        const float* xp = X + (size_t)rr * 300 + k0 + xk;
#pragma unroll
        for (int j = 0; j < 5; ++j) Xs[xk + j][xm] = xp[j];
      }
      if (MODE == MODE_NT) {
        int d = n0 + xm;
        bool ok = d < 300;
        const float* wp = W + (size_t)d * 300 + k0 + xk;
#pragma unroll
        for (int j = 0; j < 5; ++j) Ws_[xk + j][xm] = ok ? wp[j] : 0.f;
      } else {
#pragma unroll
        for (int i = 0; i < 5; ++i) {
          int flat = t + i * 256;
          int kk = flat >> 6, nn = flat & 63;
          int col = n0 + nn;
          Ws_[kk][nn] = (col < 300) ? W[(size_t)(k0 + kk) * 300 + col] : 0.f;
        }
      }
    }
    __syncthreads();
    if (act) {
#pragma unroll
      for (int kk = 0; kk < 20; ++kk) {
        const float4 a = *(const float4*)&Xs[kk][tm4];
        const float4 w = *(const float4*)&Ws_[kk][tn4];
        float av[4] = {a.x, a.y, a.z, a.w};
        float wv[4] = {w.x, w.y, w.z, w.w};
#pragma unroll
        for (int i = 0; i < 4; ++i)
#pragma unroll
          for (int j = 0; j < 4; ++j)
            acc[i][j] = fmaf(av[i], wv[j], acc[i][j]);
      }
    }
    __syncthreads();
  }
  if (!act) return;
  float bv[4] = {0.f, 0.f, 0.f, 0.f};
  if (BIAS) {
#pragma unroll
    for (int j = 0; j < 4; ++j) {
      int col = n0 + tn4 + j;
      if (col < 300) bv[j] = bias[col];
    }
  }
#pragma unroll
  for (int i = 0; i < 4; ++i) {
    int row = bm + tm4 + i;
    if (row < M) {
      float* yp = Y + (size_t)row * 300 + n0 + tn4;
#pragma unroll
      for (int j = 0; j < 4; ++j) {
        int col = n0 + tn4 + j;
        if (col < 300) yp[j] = acc[i][j] + bv[j];
      }
    }
  }
  if (Yt) {
#pragma unroll
    for (int i = 0; i < 4; ++i) {
      int row = bm + tm4 + i;
      if (row < M) {
#pragma unroll
        for (int j = 0; j < 4; ++j) {
          int col = n0 + tn4 + j;
          if (col < 300) Yt[(size_t)col * 300 + row] = acc[i][j];
        }
      }
    }
  }
}

// L0: weight precomputes. W' = Wur^T@Mr (75), A1 = Mw@Wiw (75), bias chains (3).
__global__ __launch_bounds__(256)
void weights_kernel(const float* __restrict__ Wur, const float* __restrict__ Mr,
                    const float* __restrict__ Mw, const float* __restrict__ Wiw,
                    const float* __restrict__ Wuw,
                    const float* __restrict__ bur, const float* __restrict__ buw,
                    const float* __restrict__ biw,
                    float* __restrict__ Wp, float* __restrict__ A1,
                    float* __restrict__ CGH, float* __restrict__ Bp) {
  int bid = blockIdx.x, t = threadIdx.x;
  if (bid < 75) {
    int z = bid / 25, r = bid % 25;
    gemm_tile<MODE_TN, false>(Wur + (size_t)z * 90000, Mr + (size_t)z * 90000,
                              nullptr, Wp + (size_t)z * 90000, nullptr,
                              300, (r / 5) * 64, (r % 5) * 64, t);
  } else if (bid < 150) {
    int zi = bid - 75, z = zi / 25, r = zi % 25;
    gemm_tile<MODE_NN, false>(Mw + (size_t)z * 90000, Wiw + (size_t)z * 90000,
                              nullptr, A1 + (size_t)z * 90000, nullptr,
                              300, (r / 5) * 64, (r % 5) * 64, t);
  } else {
    // bias chains: c_g = Wuw^T(Mw biw), c_h = Wiw^T(Mw^T buw), b' = Mr^T bur
    int z = bid - 150;
    __shared__ float vb[300], t1s[300], t2s[300];
    const float* Mwz = Mw + (size_t)z * 90000;
    const float* Wuwz = Wuw + (size_t)z * 90000;
    const float* Wiwz = Wiw + (size_t)z * 90000;
    const float* Mrz = Mr + (size_t)z * 90000;
    for (int k = t; k < 300; k += 256) vb[k] = biw[z * 300 + k];
    __syncthreads();
    for (int e = t; e < 300; e += 256) {
      float a = 0.f;
      for (int k = 0; k < 300; ++k) a = fmaf(Mwz[(size_t)e * 300 + k], vb[k], a);
      t1s[e] = a;
    }
    __syncthreads();
    for (int k = t; k < 300; k += 256) {
      float a = 0.f;
      for (int d = 0; d < 300; ++d) a = fmaf(Wuwz[(size_t)d * 300 + k], t1s[d], a);
      CGH[(size_t)(2 * z) * 300 + k] = a;
    }
    __syncthreads();
    for (int d = t; d < 300; d += 256) vb[d] = buw[z * 300 + d];
    __syncthreads();
    for (int e = t; e < 300; e += 256) {
      float a = 0.f;
      for (int d = 0; d < 300; ++d) a = fmaf(Mwz[(size_t)d * 300 + e], vb[d], a);
      t2s[e] = a;
    }
    __syncthreads();
    for (int k = t; k < 300; k += 256) {
      float a = 0.f;
      for (int e = 0; e < 300; ++e) a = fmaf(Wiwz[(size_t)e * 300 + k], t2s[e], a);
      CGH[(size_t)(2 * z + 1) * 300 + k] = a;
    }
    __syncthreads();
    for (int d = t; d < 300; d += 256) vb[d] = bur[z * 300 + d];
    __syncthreads();
    for (int e = t; e < 300; e += 256) {
      float a = 0.f;
      for (int d = 0; d < 300; ++d) a = fmaf(Mrz[(size_t)d * 300 + e], vb[d], a);
      Bp[z * 300 + e] = a;
    }
  }
}

// L1: gather-sum (0..7679, 10-deep ILP, sequential adds = bitwise order) +
// KG = Wuw^T @ A1 with transposed copy (75 blocks). Single gemm_tile
// instantiation -> ~11 KB LDS, gather occupancy preserved.
__global__ __launch_bounds__(320)
void gather_kg_kernel(const int* __restrict__ uRevs, const int* __restrict__ iRevs,
                      const float* __restrict__ uEmb, const float* __restrict__ iEmb,
                      const float* __restrict__ Wuw, const float* __restrict__ A1,
                      float* __restrict__ S, float* __restrict__ KG,
                      float* __restrict__ KGT) {
  int bid = blockIdx.x, t = threadIdx.x;
  if (bid < 7680) {
    int side = bid / 3840;
    int row = bid - side * 3840;
    const int* revs = side ? iRevs : uRevs;
    const float* emb = side ? iEmb : uEmb;
    __shared__ int toks[60];
    if (t < 60) toks[t] = revs[row * 60 + t];
    __syncthreads();
    if (t < 300) {
      float acc = 0.f;
#pragma unroll
      for (int l0 = 0; l0 < 60; l0 += 10) {
        float v[10];
#pragma unroll
        for (int q = 0; q < 10; ++q)
          v[q] = emb[(size_t)toks[l0 + q] * 300 + t];
#pragma unroll
        for (int q = 0; q < 10; ++q) acc += v[q];
      }
      S[(size_t)bid * 300 + t] = acc;
    }
  } else {
    int zi = bid - 7680, z = zi / 25, r = zi % 25;
    gemm_tile<MODE_TN, false>(Wuw + (size_t)z * 90000, A1 + (size_t)z * 90000,
                              nullptr, KG + (size_t)z * 90000,
                              KGT + (size_t)z * 90000,
                              300, (r / 5) * 64, (r % 5) * 64, t);
  }
}

// L2: fused review gate (bitwise-identical arithmetic to r1 path).
__global__ __launch_bounds__(256)
void gate_kernel(const float* __restrict__ S,
                 const float* __restrict__ g1w, const float* __restrict__ g1b,
                 const float* __restrict__ g2w, const float* __restrict__ g2b,
                 float* __restrict__ REV) {
  __shared__ __align__(16) float Xs[20][68];
  __shared__ __align__(16) float Ws1[20][68];
  __shared__ __align__(16) float Ws2[20][68];
  int t = threadIdx.x;
  int bm = blockIdx.x * 64;
  int n0 = blockIdx.y * 64;
  int tm4 = (t >> 4) * 4;
  int tn4 = (t & 15) * 4;
  float acc1[4][4] = {{0.f}};
  float acc2[4][4] = {{0.f}};
  int xm = t >> 2;
  int xk = (t & 3) * 5;
  for (int k0 = 0; k0 < 300; k0 += 20) {
    const float* xp = S + (size_t)(bm + xm) * 300 + k0 + xk;
#pragma unroll
    for (int j = 0; j < 5; ++j) Xs[xk + j][xm] = xp[j];
    {
      int dIdx = n0 + xm;
      bool ok = dIdx < 300;
      const float* wp1 = g1w + (size_t)dIdx * 300 + k0 + xk;
      const float* wp2 = g2w + (size_t)dIdx * 300 + k0 + xk;
#pragma unroll
      for (int j = 0; j < 5; ++j) Ws1[xk + j][xm] = ok ? wp1[j] : 0.f;
#pragma unroll
      for (int j = 0; j < 5; ++j) Ws2[xk + j][xm] = ok ? wp2[j] : 0.f;
    }
    __syncthreads();
#pragma unroll
    for (int kk = 0; kk < 20; ++kk) {
      const float4 a = *(const float4*)&Xs[kk][tm4];
      const float4 w1 = *(const float4*)&Ws1[kk][tn4];
      const float4 w2 = *(const float4*)&Ws2[kk][tn4];
      float av[4] = {a.x, a.y, a.z, a.w};
      float w1v[4] = {w1.x, w1.y, w1.z, w1.w};
      float w2v[4] = {w2.x, w2.y, w2.z, w2.w};
#pragma unroll
      for (int i = 0; i < 4; ++i)
#pragma unroll
        for (int j = 0; j < 4; ++j) {
          acc1[i][j] = fmaf(av[i], w1v[j], acc1[i][j]);
          acc2[i][j] = fmaf(av[i], w2v[j], acc2[i][j]);
        }
    }
    __syncthreads();
  }
#pragma unroll
  for (int i = 0; i < 4; ++i) {
    int row = bm + tm4 + i;
    float* yp = REV + (size_t)row * 300 + n0 + tn4;
#pragma unroll
    for (int j = 0; j < 4; ++j) {
      int col = n0 + tn4 + j;
      if (col < 300) {
        float a = acc1[i][j] + g1b[col];
        float b = acc2[i][j] + g2b[col];
        yp[j] = (1.f / (1.f + expf(-a))) * tanhf(b);
      }
    }
  }
}

// L3: TP/IP GEMMs, 128x64 tile, 8x4 micro (3 ds_read_b128 per 32 FMA).
// z<3: NN (W', bias Bp) ; z>=3: NT (Wir, bias bir). K-order per output
// identical to r4 -> TP/IP bitwise identical -> selections frozen.
__global__ __launch_bounds__(256)
void rev128_kernel(Ptr6 P) {
  int z = blockIdx.z;
  const bool nt = z >= 3;
  const float* __restrict__ X = P.X[z];
  const float* __restrict__ W = P.W[z];
  const float* __restrict__ bias = P.Bb[z];
  float* __restrict__ Y = P.Y[z];
  __shared__ __align__(16) float Xs[20][136];
  __shared__ __align__(16) float Ws_[20][68];
  int t = threadIdx.x;
  int bm = blockIdx.x * 128, n0 = blockIdx.y * 64;
  int tm8 = (t >> 4) * 8, tn4 = (t & 15) * 4;
  float acc[8][4] = {{0.f}};
  int xm = t >> 1, xk = (t & 1) * 10;
  int wm = t >> 2, wk = (t & 3) * 5;
  for (int k0 = 0; k0 < 300; k0 += 20) {
    const float* xp = X + (size_t)(bm + xm) * 300 + k0 + xk;
#pragma unroll
    for (int j = 0; j < 10; ++j) Xs[xk + j][xm] = xp[j];
    if (nt) {
      int d = n0 + wm;
      bool ok = d < 300;
      const float* wp = W + (size_t)d * 300 + k0 + wk;
#pragma unroll
      for (int j = 0; j < 5; ++j) Ws_[wk + j][wm] = ok ? wp[j] : 0.f;
    } else {
#pragma unroll
      for (int i = 0; i < 5; ++i) {
        int flat = t + i * 256;
        int kk = flat >> 6, nn = flat & 63;
        int col = n0 + nn;
        Ws_[kk][nn] = (col < 300) ? W[(size_t)(k0 + kk) * 300 + col] : 0.f;
      }
    }
    __syncthreads();
#pragma unroll
    for (int kk = 0; kk < 20; ++kk) {
      const float4 a0 = *(const float4*)&Xs[kk][tm8];
      const float4 a1 = *(const float4*)&Xs[kk][tm8 + 4];
      const float4 w = *(const float4*)&Ws_[kk][tn4];
      float av[8] = {a0.x, a0.y, a0.z, a0.w, a1.x, a1.y, a1.z, a1.w};
      float wv[4] = {w.x, w.y, w.z, w.w};
#pragma unroll
      for (int i = 0; i < 8; ++i)
#pragma unroll
        for (int j = 0; j < 4; ++j)
          acc[i][j] = fmaf(av[i], wv[j], acc[i][j]);
    }
    __syncthreads();
  }
  float bv[4];
#pragma unroll
  for (int j = 0; j < 4; ++j) {
    int col = n0 + tn4 + j;
    bv[j] = (col < 300) ? bias[col] : 0.f;
  }
#pragma unroll
  for (int i = 0; i < 8; ++i) {
    float* yp = Y + (size_t)(bm + tm8 + i) * 300 + n0 + tn4;
#pragma unroll
    for (int j = 0; j < 4; ++j) {
      int col = n0 + tn4 + j;
      if (col < 300) yp[j] = acc[i][j] + bv[j];
    }
  }
}

// L5: batched NN GEMM with per-z pointer sets (GH, M=128).
template <bool BIAS>
__global__ __launch_bounds__(256)
void nn6_kernel(Ptr6 P, int M) {
  int z = blockIdx.z;
  gemm_tile<MODE_NN, BIAS>(P.X[z], P.W[z], P.Bb[z], P.Y[z], nullptr,
                           M, blockIdx.x * 64, blockIdx.y * 64, threadIdx.x);
}

// L4: review scores + gumbel-argmax (bitwise r1 math) + fused MEAN.
__global__ __launch_bounds__(256)
void argmax_mean_kernel(const float* __restrict__ Tall, const float* __restrict__ Iall,
                        const int* __restrict__ uRevs, const int* __restrict__ iRevs,
                        const float* __restrict__ uEmb, const float* __restrict__ iEmb,
                        int* __restrict__ idxU, int* __restrict__ idxI,
                        float* __restrict__ MEAN, GKeys K) {
  int b = blockIdx.x, z = blockIdx.y, t = threadIdx.x;
  uint32_t ku0 = K.v[z * 4], ku1 = K.v[z * 4 + 1];
  uint32_t ki0 = K.v[z * 4 + 2], ki1 = K.v[z * 4 + 3];
  __shared__ float Is[30 * 301];
  __shared__ float Sc[900];
  __shared__ float us[30], vs[30];
  __shared__ int selU, selI;
  __shared__ int toksI_s[60], toksU_s[60];
  const float* Tb = Tall + (size_t)z * 1152000 + (size_t)b * 9000;
  const float* Ib = Iall + (size_t)z * 1152000 + (size_t)b * 9000;
  for (int e = t; e < 9000; e += 256) Is[(e / 300) * 301 + (e % 300)] = Ib[e];
  __syncthreads();
  for (int id = t; id < 900; id += 256) {
    int r = id / 30, c = id - r * 30;
    const float* tr = Tb + r * 300;
    const float* ic = Is + c * 301;
    float acc = 0.f;
    for (int k = 0; k < 300; ++k) acc = fmaf(tr[k], ic[k], acc);
    Sc[id] = acc;
  }
  __syncthreads();
  if (t < 30) {
    float m = -3.4e38f;
    for (int c = 0; c < 30; ++c) m = fmaxf(m, Sc[t * 30 + c]);
    us[t] = m + jax_gumbel32(ku0, ku1, (uint32_t)(b * 30 + t));
  } else if (t >= 64 && t < 94) {
    int s = t - 64;
    float m = -3.4e38f;
    for (int r = 0; r < 30; ++r) m = fmaxf(m, Sc[r * 30 + s]);
    vs[s] = m + jax_gumbel32(ki0, ki1, (uint32_t)(b * 30 + s));
  }
  __syncthreads();
  if (t == 0) {
    int best = 0; float bvv = us[0];
    for (int r = 1; r < 30; ++r) { if (us[r] > bvv) { bvv = us[r]; best = r; } }
    idxU[z * 128 + b] = best; selU = best;
  } else if (t == 1) {
    int best = 0; float bvv = vs[0];
    for (int s = 1; s < 30; ++s) { if (vs[s] > bvv) { bvv = vs[s]; best = s; } }
    idxI[z * 128 + b] = best; selI = best;
  }
  __syncthreads();
  if (t < 60) toksI_s[t] = iRevs[(b * 30 + selI) * 60 + t];
  else if (t >= 64 && t < 124) toksU_s[t - 64] = uRevs[(b * 30 + selU) * 60 + (t - 64)];
  __syncthreads();
  for (int dd = t; dd < 600; dd += 256) {
    int side = dd / 300;
    int d = dd - side * 300;
    const int* tk = side ? toksU_s : toksI_s;
    const float* em = side ? uEmb : iEmb;
    float acc = 0.f;
#pragma unroll
    for (int l0 = 0; l0 < 60; l0 += 10) {
      float v[10];
#pragma unroll
      for (int q = 0; q < 10; ++q)
        v[q] = em[(size_t)tk[l0 + q] * 300 + d];
#pragma unroll
      for (int q = 0; q < 10; ++q) acc += v[q];
    }
    MEAN[((size_t)(2 * z + side) * 128 + b) * 300 + d] = acc * (1.f / 60.f);
  }
}

// L6: per (b, side, p): scores = word rows . gvec; softmax; weighted sum.
__global__ __launch_bounds__(256)
void word_rep_kernel(const int* __restrict__ uRevs, const int* __restrict__ iRevs,
                     const float* __restrict__ uEmb, const float* __restrict__ iEmb,
                     const int* __restrict__ idxU, const int* __restrict__ idxI,
                     const float* __restrict__ GH, float* __restrict__ JNT) {
  int b = blockIdx.x, side = blockIdx.y, p = blockIdx.z;
  const int* revs = side ? iRevs : uRevs;
  const float* emb = side ? iEmb : uEmb;
  int idx = side ? idxI[p * 128 + b] : idxU[p * 128 + b];
  const float* gv = GH + ((size_t)(p * 2 + side) * 128 + b) * 300;
  __shared__ int toks[60];
  __shared__ float g_s[300];
  __shared__ float score[60];
  __shared__ float probs[64];
  int t = threadIdx.x;
  if (t < 60) toks[t] = revs[(b * 30 + idx) * 60 + t];
  for (int d = t; d < 300; d += 256) g_s[d] = gv[d];
  __syncthreads();
  int w = t >> 6, j = t & 63;
  for (int i = 0; i < 15; ++i) {
    int l = w * 15 + i;
    const float* er = emb + (size_t)toks[l] * 300;
    float partial = 0.f;
#pragma unroll
    for (int c = 0; c < 5; ++c) {
      int k = j + c * 64;
      if (k < 300) partial = fmaf(er[k], g_s[k], partial);
    }
#pragma unroll
    for (int m = 32; m >= 1; m >>= 1) partial += __shfl_xor(partial, m);
    if (j == 0) score[l] = partial;
  }
  __syncthreads();
  if (w == 0) {
    float s = (j < 60) ? score[j] : -3.4e38f;
    float m = s;
#pragma unroll
    for (int mm = 32; mm >= 1; mm >>= 1) m = fmaxf(m, __shfl_xor(m, mm));
    float e = (j < 60) ? expf(s - m) : 0.f;
    float sum = e;
#pragma unroll
    for (int mm = 32; mm >= 1; mm >>= 1) sum += __shfl_xor(sum, mm);
    if (j < 60) probs[j] = e / sum;
  }
  __syncthreads();
  float* outp = JNT + (size_t)b * 1800 + side * 900 + p * 300;
  for (int d = t; d < 300; d += 256) {
    float acc = 0.f;
    for (int l0 = 0; l0 < 60; l0 += 6) {
      float e0 = emb[(size_t)toks[l0 + 0] * 300 + d];
      float e1 = emb[(size_t)toks[l0 + 1] * 300 + d];
      float e2 = emb[(size_t)toks[l0 + 2] * 300 + d];
      float e3 = emb[(size_t)toks[l0 + 3] * 300 + d];
      float e4 = emb[(size_t)toks[l0 + 4] * 300 + d];
      float e5 = emb[(size_t)toks[l0 + 5] * 300 + d];
      acc = fmaf(probs[l0 + 0], e0, acc);
      acc = fmaf(probs[l0 + 1], e1, acc);
      acc = fmaf(probs[l0 + 2], e2, acc);
      acc = fmaf(probs[l0 + 3], e3, acc);
      acc = fmaf(probs[l0 + 4], e4, acc);
      acc = fmaf(probs[l0 + 5], e5, acc);
    }
    outp[d] = acc;
  }
}

// L7: factorization machine.
__global__ __launch_bounds__(64)
void fm_kernel(const float* __restrict__ JNT, const float* __restrict__ w0,
               const float* __restrict__ fw, const float* __restrict__ fv,
               float* __restrict__ out) {
  int b = blockIdx.x, lane = threadIdx.x;
  const float* x = JNT + (size_t)b * 1800;
  float lin = 0.f;
  float t1[10], t2[10];
#pragma unroll
  for (int k = 0; k < 10; ++k) { t1[k] = 0.f; t2[k] = 0.f; }
  for (int j = lane; j < 1800; j += 64) {
    float xv = x[j];
    lin = fmaf(fw[j], xv, lin);
    float xx = xv * xv;
#pragma unroll
    for (int k = 0; k < 10; ++k) {
      float v = fv[j * 10 + k];
      t1[k] = fmaf(xv, v, t1[k]);
      t2[k] = fmaf(xx, v * v, t2[k]);
    }
  }
#pragma unroll
  for (int m = 32; m >= 1; m >>= 1) {
    lin += __shfl_xor(lin, m);
#pragma unroll
    for (int k = 0; k < 10; ++k) {
      t1[k] += __shfl_xor(t1[k], m);
      t2[k] += __shfl_xor(t2[k], m);
    }
  }
  if (lane == 0) {
    float inter = 0.f;
#pragma unroll
    for (int k = 0; k < 10; ++k) inter += t1[k] * t1[k] - t2[k];
    out[b] = w0[0] + lin + 0.5f * inter;
  }
}

extern "C" void kernel_launch(void* const* d_in, const int* in_sizes, int n_in,
                              void* d_out, int out_size, void* d_ws, size_t ws_size,
                              hipStream_t stream) {
  (void)in_sizes; (void)n_in; (void)out_size;
  const int*   uRevs = (const int*)d_in[0];
  const int*   iRevs = (const int*)d_in[1];
  const float* uEmb  = (const float*)d_in[2];
  const float* iEmb  = (const float*)d_in[3];
  const float* g1w   = (const float*)d_in[4];
  const float* g1b   = (const float*)d_in[5];
  const float* g2w   = (const float*)d_in[6];
  const float* g2b   = (const float*)d_in[7];
  const float* Mr    = (const float*)d_in[8];
  const float* Wur   = (const float*)d_in[9];
  const float* bur   = (const float*)d_in[10];
  const float* Wir   = (const float*)d_in[11];
  const float* bir   = (const float*)d_in[12];
  const float* Mw    = (const float*)d_in[13];
  const float* Wuw   = (const float*)d_in[14];
  const float* buw   = (const float*)d_in[15];
  const float* Wiw   = (const float*)d_in[16];
  const float* biw   = (const float*)d_in[17];
  const float* fmw0  = (const float*)d_in[18];
  const float* fmw   = (const float*)d_in[19];
  const float* fmv   = (const float*)d_in[20];
  float* out = (float*)d_out;

  float* ws = (float*)d_ws;
  // Layout (floats), lifetime overlays:
  //   S @0 (2,304,000) L1..L2 ; TPall @0 (3,456,000) L3..L4
  //   REV @3,456,000 (2,304,000) L2..L3 ; MEAN @3,456,000 (230,400) L4..
  //   GH @3,686,400 ; JNT @3,916,800 ; idx @4,147,200 (768 int)
  //   IPall @5,760,000 (3,456,000) L3..L4
  //   A1 @9,216,000 ; Wp @9,486,000 ; KG @9,756,000 ; KGT @10,026,000 ;
  //   Bp @10,296,000 (900) ; CGH @10,296,900 (1800)
  const size_t NEED_BYTES = (size_t)10298700 * 4;
  if (ws_size < NEED_BYTES) return;

  float* S     = ws + 0;
  float* TPall = ws + 0;
  float* REV   = ws + 3456000;
  float* MEAN  = ws + 3456000;
  float* GH    = ws + 3686400;
  float* JNT   = ws + 3916800;
  int*   idxU  = (int*)(ws + 4147200);
  int*   idxI  = idxU + 384;
  float* IPall = ws + 5760000;
  float* A1    = ws + 9216000;
  float* Wp    = ws + 9486000;
  float* KG    = ws + 9756000;
  float* KGT   = ws + 10026000;
  float* Bp    = ws + 10296000;
  float* CGH   = ws + 10296900;

  // L0: weight precomputes (W', A1, bias chains)
  weights_kernel<<<dim3(153), dim3(256), 0, stream>>>(
      Wur, Mr, Mw, Wiw, Wuw, bur, buw, biw, Wp, A1, CGH, Bp);

  // L1: gather-sum + KG (+KGT)
  gather_kg_kernel<<<dim3(7755), dim3(320), 0, stream>>>(
      uRevs, iRevs, uEmb, iEmb, Wuw, A1, S, KG, KGT);

  // L2: review gate
  gate_kernel<<<dim3(120, 5), dim3(256), 0, stream>>>(
      S, g1w, g1b, g2w, g2b, REV);

  // L3: TP = REV_u @ W' + b' (NN) ; IP = REV_i @ Wir^T + bir (NT)
  {
    Ptr6 P;
    for (int z = 0; z < 3; ++z) {
      P.X[z] = REV;
      P.W[z] = Wp + (size_t)z * 90000;
      P.Bb[z] = Bp + z * 300;
      P.Y[z] = TPall + (size_t)z * 1152000;
      P.X[z + 3] = REV + (size_t)3840 * 300;
      P.W[z + 3] = Wir + (size_t)z * 90000;
      P.Bb[z + 3] = bir + z * 300;
      P.Y[z + 3] = IPall + (size_t)z * 1152000;
    }
    rev128_kernel<<<dim3(30, 5, 6), dim3(256), 0, stream>>>(P);
  }

  // L4: gumbel-argmax + fused MEAN
  {
    GKeys K;
    for (int p = 0; p < 3; ++p) {
      tf2x32(0u, 42u, 0u, (uint32_t)(2 * p),     &K.v[p * 4],     &K.v[p * 4 + 1]);
      tf2x32(0u, 42u, 0u, (uint32_t)(2 * p + 1), &K.v[p * 4 + 2], &K.v[p * 4 + 3]);
    }
    argmax_mean_kernel<<<dim3(128, 3), dim3(256), 0, stream>>>(
        TPall, IPall, uRevs, iRevs, uEmb, iEmb, idxU, idxI, MEAN, K);
  }

  // L5: GH[2p] = MEAN_i @ KG^T + c_g ; GH[2p+1] = MEAN_u @ KG + c_h
  {
    Ptr6 P;
    for (int zz = 0; zz < 6; ++zz) {
      int p = zz >> 1;
      P.X[zz] = MEAN + (size_t)zz * 38400;
      P.W[zz] = (zz & 1) ? KG + (size_t)p * 90000 : KGT + (size_t)p * 90000;
      P.Bb[zz] = CGH + (size_t)zz * 300;
      P.Y[zz] = GH + (size_t)zz * 38400;
    }
    nn6_kernel<true><<<dim3(2, 5, 6), dim3(256), 0, stream>>>(P, 128);
  }

  // L6: word-level softmax representations
  word_rep_kernel<<<dim3(128, 2, 3), dim3(256), 0, stream>>>(
      uRevs, iRevs, uEmb, iEmb, idxU, idxI, GH, JNT);

  // L7: factorization machine
  fm_kernel<<<dim3(128), dim3(64), 0, stream>>>(JNT, fmw0, fmw, fmv, out);
}

// Round 6
// 397.086 us; speedup vs baseline: 1.1316x; 1.0900x over previous
//
#include <hip/hip_runtime.h>
#include <stdint.h>
#include <math.h>

// ---------------------------------------------------------------------------
// MPCN (B=128, R=30, L=60, D=300, V=50000, P=3), f32 end-to-end.
// Round 6: gather back to a minimal-resource standalone kernel (4 rows/block,
// float4 lanes, 10-deep ILP); gemm_tile takes an LDS arena so fusing KG into
// gate_kernel adds no LDS. Selection-critical math bitwise-stable vs r5.
// ---------------------------------------------------------------------------

__host__ __device__ static inline void tf2x32(uint32_t k0, uint32_t k1,
                                              uint32_t x0, uint32_t x1,
                                              uint32_t* o0, uint32_t* o1) {
  uint32_t ks[3] = {k0, k1, k0 ^ k1 ^ 0x1BD11BDAu};
  x0 += ks[0]; x1 += ks[1];
  const int rotA[4] = {13, 15, 26, 6};
  const int rotB[4] = {17, 29, 16, 24};
#pragma unroll
  for (int i = 0; i < 5; ++i) {
    const int* rot = ((i & 1) == 0) ? rotA : rotB;
#pragma unroll
    for (int j = 0; j < 4; ++j) {
      x0 += x1;
      x1 = (x1 << rot[j]) | (x1 >> (32 - rot[j]));
      x1 ^= x0;
    }
    x0 += ks[(i + 1) % 3];
    x1 += ks[(i + 2) % 3] + (uint32_t)(i + 1);
  }
  *o0 = x0; *o1 = x1;
}

struct GKeys { uint32_t v[12]; };
struct Ptr6 {
  const float* X[6];
  const float* W[6];
  const float* Bb[6];
  float*       Y[6];
};

__device__ static inline float jax_gumbel32(uint32_t k0, uint32_t k1, uint32_t idx) {
  uint32_t o0, o1;
  tf2x32(k0, k1, 0u, idx, &o0, &o1);
  uint32_t bits = o0 ^ o1;
  float f = __uint_as_float((bits >> 9) | 0x3f800000u) - 1.0f;
  float u = (f > 0.0f) ? f : 1.17549435e-38f;
  return -logf(-logf(u));
}

#define MODE_NN 0
#define MODE_NT 1
#define MODE_TN 2

// 64x64 f32 GEMM tile, K=N=300, ld=300, on a caller-provided LDS arena
// (needs 2*20*68 floats = 10880 B). Blocks >=256 threads; extras idle but
// reach barriers. Optional transposed second output Yt.
template <int MODE, bool BIAS>
__device__ __forceinline__ void gemm_tile(float* __restrict__ sm,
                                          const float* __restrict__ X,
                                          const float* __restrict__ W,
                                          const float* __restrict__ bias,
                                          float* __restrict__ Y,
                                          float* __restrict__ Yt,
                                          int M, int bm, int n0, int t) {
  float (*Xs)[68] = (float(*)[68])sm;
  float (*Ws_)[68] = (float(*)[68])(sm + 20 * 68);
  const bool act = t < 256;
  int tm4 = ((t >> 4) & 15) * 4;
  int tn4 = (t & 15) * 4;
  float acc[4][4] = {{0.f}};
  int xm = t >> 2;
  int xk = (t & 3) * 5;
  for (int k0 = 0; k0 < 300; k0 += 20) {
    if (act) {
      if (MODE == MODE_TN) {
#pragma unroll
        for (int i = 0; i < 5; ++i) {
          int flat = t + i * 256;
          int kk = flat >> 6, nn = flat & 63;
          int r = bm + nn;
          Xs[kk][nn] = (r < 300) ? X[(size_t)(k0 + kk) * 300 + r] : 0.f;
        }
      } else {
        int rr = bm + xm; if (rr >= M) rr = M - 1;
        const float* xp = X + (size_t)rr * 300 + k0 + xk;
#pragma unroll
        for (int j = 0; j < 5; ++j) Xs[xk + j][xm] = xp[j];
      }
      if (MODE == MODE_NT) {
        int d = n0 + xm;
        bool ok = d < 300;
        const float* wp = W + (size_t)d * 300 + k0 + xk;
#pragma unroll
        for (int j = 0; j < 5; ++j) Ws_[xk + j][xm] = ok ? wp[j] : 0.f;
      } else {
#pragma unroll
        for (int i = 0; i < 5; ++i) {
          int flat = t + i * 256;
          int kk = flat >> 6, nn = flat & 63;
          int col = n0 + nn;
          Ws_[kk][nn] = (col < 300) ? W[(size_t)(k0 + kk) * 300 + col] : 0.f;
        }
      }
    }
    __syncthreads();
    if (act) {
#pragma unroll
      for (int kk = 0; kk < 20; ++kk) {
        const float4 a = *(const float4*)&Xs[kk][tm4];
        const float4 w = *(const float4*)&Ws_[kk][tn4];
        float av[4] = {a.x, a.y, a.z, a.w};
        float wv[4] = {w.x, w.y, w.z, w.w};
#pragma unroll
        for (int i = 0; i < 4; ++i)
#pragma unroll
          for (int j = 0; j < 4; ++j)
            acc[i][j] = fmaf(av[i], wv[j], acc[i][j]);
      }
    }
    __syncthreads();
  }
  if (!act) return;
  float bv[4] = {0.f, 0.f, 0.f, 0.f};
  if (BIAS) {
#pragma unroll
    for (int j = 0; j < 4; ++j) {
      int col = n0 + tn4 + j;
      if (col < 300) bv[j] = bias[col];
    }
  }
#pragma unroll
  for (int i = 0; i < 4; ++i) {
    int row = bm + tm4 + i;
    if (row < M) {
      float* yp = Y + (size_t)row * 300 + n0 + tn4;
#pragma unroll
      for (int j = 0; j < 4; ++j) {
        int col = n0 + tn4 + j;
        if (col < 300) yp[j] = acc[i][j] + bv[j];
      }
    }
  }
  if (Yt) {
#pragma unroll
    for (int i = 0; i < 4; ++i) {
      int row = bm + tm4 + i;
      if (row < 300) {
#pragma unroll
        for (int j = 0; j < 4; ++j) {
          int col = n0 + tn4 + j;
          if (col < 300) Yt[(size_t)col * 300 + row] = acc[i][j];
        }
      }
    }
  }
}

// L0: weight precomputes. W' = Wur^T@Mr (75), A1 = Mw@Wiw (75), bias chains (3).
__global__ __launch_bounds__(256)
void weights_kernel(const float* __restrict__ Wur, const float* __restrict__ Mr,
                    const float* __restrict__ Mw, const float* __restrict__ Wiw,
                    const float* __restrict__ Wuw,
                    const float* __restrict__ bur, const float* __restrict__ buw,
                    const float* __restrict__ biw,
                    float* __restrict__ Wp, float* __restrict__ A1,
                    float* __restrict__ CGH, float* __restrict__ Bp) {
  __shared__ __align__(16) float arena[2720];  // 10880 B
  int bid = blockIdx.x, t = threadIdx.x;
  if (bid < 75) {
    int z = bid / 25, r = bid % 25;
    gemm_tile<MODE_TN, false>(arena, Wur + (size_t)z * 90000, Mr + (size_t)z * 90000,
                              nullptr, Wp + (size_t)z * 90000, nullptr,
                              300, (r / 5) * 64, (r % 5) * 64, t);
  } else if (bid < 150) {
    int zi = bid - 75, z = zi / 25, r = zi % 25;
    gemm_tile<MODE_NN, false>(arena, Mw + (size_t)z * 90000, Wiw + (size_t)z * 90000,
                              nullptr, A1 + (size_t)z * 90000, nullptr,
                              300, (r / 5) * 64, (r % 5) * 64, t);
  } else {
    // bias chains: c_g = Wuw^T(Mw biw), c_h = Wiw^T(Mw^T buw), b' = Mr^T bur
    int z = bid - 150;
    float* vb = arena;
    float* t1s = arena + 304;
    float* t2s = arena + 608;
    const float* Mwz = Mw + (size_t)z * 90000;
    const float* Wuwz = Wuw + (size_t)z * 90000;
    const float* Wiwz = Wiw + (size_t)z * 90000;
    const float* Mrz = Mr + (size_t)z * 90000;
    for (int k = t; k < 300; k += 256) vb[k] = biw[z * 300 + k];
    __syncthreads();
    for (int e = t; e < 300; e += 256) {
      float a = 0.f;
      for (int k = 0; k < 300; ++k) a = fmaf(Mwz[(size_t)e * 300 + k], vb[k], a);
      t1s[e] = a;
    }
    __syncthreads();
    for (int k = t; k < 300; k += 256) {
      float a = 0.f;
      for (int d = 0; d < 300; ++d) a = fmaf(Wuwz[(size_t)d * 300 + k], t1s[d], a);
      CGH[(size_t)(2 * z) * 300 + k] = a;
    }
    __syncthreads();
    for (int d = t; d < 300; d += 256) vb[d] = buw[z * 300 + d];
    __syncthreads();
    for (int e = t; e < 300; e += 256) {
      float a = 0.f;
      for (int d = 0; d < 300; ++d) a = fmaf(Mwz[(size_t)d * 300 + e], vb[d], a);
      t2s[e] = a;
    }
    __syncthreads();
    for (int k = t; k < 300; k += 256) {
      float a = 0.f;
      for (int e = 0; e < 300; ++e) a = fmaf(Wiwz[(size_t)e * 300 + k], t2s[e], a);
      CGH[(size_t)(2 * z + 1) * 300 + k] = a;
    }
    __syncthreads();
    for (int d = t; d < 300; d += 256) vb[d] = bur[z * 300 + d];
    __syncthreads();
    for (int e = t; e < 300; e += 256) {
      float a = 0.f;
      for (int d = 0; d < 300; ++d) a = fmaf(Mrz[(size_t)d * 300 + e], vb[d], a);
      Bp[z * 300 + e] = a;
    }
  }
}

// L1: gather-sum, minimal-resource. 4 rows/block, float4 per thread
// (75 threads/row), 10-deep load batching, sequential adds (bitwise order
// per output dim identical to the scalar version).
__global__ __launch_bounds__(320)
void gather_kernel(const int* __restrict__ uRevs, const int* __restrict__ iRevs,
                   const float* __restrict__ uEmb, const float* __restrict__ iEmb,
                   float* __restrict__ S) {
  int bid = blockIdx.x;   // 0..1919
  int t = threadIdx.x;
  __shared__ int toks[4][60];
  if (t < 240) {
    int rr = t / 60, l = t - rr * 60;
    int grow = bid * 4 + rr;
    int side = grow / 3840;
    int row = grow - side * 3840;
    const int* revs = side ? iRevs : uRevs;
    toks[rr][l] = revs[row * 60 + l];
  }
  __syncthreads();
  if (t < 300) {
    int sub = t / 75;
    int q4 = (t - sub * 75) * 4;
    int grow = bid * 4 + sub;
    int side = grow / 3840;
    const float* emb = side ? iEmb : uEmb;
    const int* tk = toks[sub];
    float ax = 0.f, ay = 0.f, az = 0.f, aw = 0.f;
#pragma unroll
    for (int l0 = 0; l0 < 60; l0 += 10) {
      float4 v[10];
#pragma unroll
      for (int qq = 0; qq < 10; ++qq)
        v[qq] = *(const float4*)&emb[(size_t)tk[l0 + qq] * 300 + q4];
#pragma unroll
      for (int qq = 0; qq < 10; ++qq) {
        ax += v[qq].x; ay += v[qq].y; az += v[qq].z; aw += v[qq].w;
      }
    }
    float4 r = {ax, ay, az, aw};
    *(float4*)&S[(size_t)grow * 300 + q4] = r;
  }
}

// L2: fused review gate (600 blocks, bitwise r1 arithmetic) + KG = Wuw^T@A1
// with transposed copy (75 blocks). Shared LDS arena -> 16.3 KB total.
__global__ __launch_bounds__(256)
void gate_kernel(const float* __restrict__ S,
                 const float* __restrict__ g1w, const float* __restrict__ g1b,
                 const float* __restrict__ g2w, const float* __restrict__ g2b,
                 float* __restrict__ REV,
                 const float* __restrict__ Wuw, const float* __restrict__ A1,
                 float* __restrict__ KG, float* __restrict__ KGT) {
  __shared__ __align__(16) float arena[4080];  // 16320 B
  int bid = blockIdx.x, t = threadIdx.x;
  if (bid < 600) {
    float (*Xs)[68] = (float(*)[68])arena;
    float (*Ws1)[68] = (float(*)[68])(arena + 1360);
    float (*Ws2)[68] = (float(*)[68])(arena + 2720);
    int bm = (bid / 5) * 64;
    int n0 = (bid % 5) * 64;
    int tm4 = (t >> 4) * 4;
    int tn4 = (t & 15) * 4;
    float acc1[4][4] = {{0.f}};
    float acc2[4][4] = {{0.f}};
    int xm = t >> 2;
    int xk = (t & 3) * 5;
    for (int k0 = 0; k0 < 300; k0 += 20) {
      const float* xp = S + (size_t)(bm + xm) * 300 + k0 + xk;
#pragma unroll
      for (int j = 0; j < 5; ++j) Xs[xk + j][xm] = xp[j];
      {
        int dIdx = n0 + xm;
        bool ok = dIdx < 300;
        const float* wp1 = g1w + (size_t)dIdx * 300 + k0 + xk;
        const float* wp2 = g2w + (size_t)dIdx * 300 + k0 + xk;
#pragma unroll
        for (int j = 0; j < 5; ++j) Ws1[xk + j][xm] = ok ? wp1[j] : 0.f;
#pragma unroll
        for (int j = 0; j < 5; ++j) Ws2[xk + j][xm] = ok ? wp2[j] : 0.f;
      }
      __syncthreads();
#pragma unroll
      for (int kk = 0; kk < 20; ++kk) {
        const float4 a = *(const float4*)&Xs[kk][tm4];
        const float4 w1 = *(const float4*)&Ws1[kk][tn4];
        const float4 w2 = *(const float4*)&Ws2[kk][tn4];
        float av[4] = {a.x, a.y, a.z, a.w};
        float w1v[4] = {w1.x, w1.y, w1.z, w1.w};
        float w2v[4] = {w2.x, w2.y, w2.z, w2.w};
#pragma unroll
        for (int i = 0; i < 4; ++i)
#pragma unroll
          for (int j = 0; j < 4; ++j) {
            acc1[i][j] = fmaf(av[i], w1v[j], acc1[i][j]);
            acc2[i][j] = fmaf(av[i], w2v[j], acc2[i][j]);
          }
      }
      __syncthreads();
    }
#pragma unroll
    for (int i = 0; i < 4; ++i) {
      int row = bm + tm4 + i;
      float* yp = REV + (size_t)row * 300 + n0 + tn4;
#pragma unroll
      for (int j = 0; j < 4; ++j) {
        int col = n0 + tn4 + j;
        if (col < 300) {
          float a = acc1[i][j] + g1b[col];
          float b = acc2[i][j] + g2b[col];
          yp[j] = (1.f / (1.f + expf(-a))) * tanhf(b);
        }
      }
    }
  } else {
    int zi = bid - 600, z = zi / 25, r = zi % 25;
    gemm_tile<MODE_TN, false>(arena, Wuw + (size_t)z * 90000, A1 + (size_t)z * 90000,
                              nullptr, KG + (size_t)z * 90000,
                              KGT + (size_t)z * 90000,
                              300, (r / 5) * 64, (r % 5) * 64, t);
  }
}

// L3: TP/IP GEMMs, 128x64 tile, 8x4 micro. z<3: NN (W', Bp); z>=3: NT (Wir, bir).
__global__ __launch_bounds__(256)
void rev128_kernel(Ptr6 P) {
  int z = blockIdx.z;
  const bool nt = z >= 3;
  const float* __restrict__ X = P.X[z];
  const float* __restrict__ W = P.W[z];
  const float* __restrict__ bias = P.Bb[z];
  float* __restrict__ Y = P.Y[z];
  __shared__ __align__(16) float Xs[20][136];
  __shared__ __align__(16) float Ws_[20][68];
  int t = threadIdx.x;
  int bm = blockIdx.x * 128, n0 = blockIdx.y * 64;
  int tm8 = (t >> 4) * 8, tn4 = (t & 15) * 4;
  float acc[8][4] = {{0.f}};
  int xm = t >> 1, xk = (t & 1) * 10;
  int wm = t >> 2, wk = (t & 3) * 5;
  for (int k0 = 0; k0 < 300; k0 += 20) {
    const float* xp = X + (size_t)(bm + xm) * 300 + k0 + xk;
#pragma unroll
    for (int j = 0; j < 10; ++j) Xs[xk + j][xm] = xp[j];
    if (nt) {
      int d = n0 + wm;
      bool ok = d < 300;
      const float* wp = W + (size_t)d * 300 + k0 + wk;
#pragma unroll
      for (int j = 0; j < 5; ++j) Ws_[wk + j][wm] = ok ? wp[j] : 0.f;
    } else {
#pragma unroll
      for (int i = 0; i < 5; ++i) {
        int flat = t + i * 256;
        int kk = flat >> 6, nn = flat & 63;
        int col = n0 + nn;
        Ws_[kk][nn] = (col < 300) ? W[(size_t)(k0 + kk) * 300 + col] : 0.f;
      }
    }
    __syncthreads();
#pragma unroll
    for (int kk = 0; kk < 20; ++kk) {
      const float4 a0 = *(const float4*)&Xs[kk][tm8];
      const float4 a1 = *(const float4*)&Xs[kk][tm8 + 4];
      const float4 w = *(const float4*)&Ws_[kk][tn4];
      float av[8] = {a0.x, a0.y, a0.z, a0.w, a1.x, a1.y, a1.z, a1.w};
      float wv[4] = {w.x, w.y, w.z, w.w};
#pragma unroll
      for (int i = 0; i < 8; ++i)
#pragma unroll
        for (int j = 0; j < 4; ++j)
          acc[i][j] = fmaf(av[i], wv[j], acc[i][j]);
    }
    __syncthreads();
  }
  float bv[4];
#pragma unroll
  for (int j = 0; j < 4; ++j) {
    int col = n0 + tn4 + j;
    bv[j] = (col < 300) ? bias[col] : 0.f;
  }
#pragma unroll
  for (int i = 0; i < 8; ++i) {
    float* yp = Y + (size_t)(bm + tm8 + i) * 300 + n0 + tn4;
#pragma unroll
    for (int j = 0; j < 4; ++j) {
      int col = n0 + tn4 + j;
      if (col < 300) yp[j] = acc[i][j] + bv[j];
    }
  }
}

// L5: batched NN GEMM with per-z pointer sets (GH, M=128).
template <bool BIAS>
__global__ __launch_bounds__(256)
void nn6_kernel(Ptr6 P, int M) {
  __shared__ __align__(16) float arena[2720];
  int z = blockIdx.z;
  gemm_tile<MODE_NN, BIAS>(arena, P.X[z], P.W[z], P.Bb[z], P.Y[z], nullptr,
                           M, blockIdx.x * 64, blockIdx.y * 64, threadIdx.x);
}

// L4: review scores + gumbel-argmax (bitwise r1 math) + fused MEAN.
__global__ __launch_bounds__(256)
void argmax_mean_kernel(const float* __restrict__ Tall, const float* __restrict__ Iall,
                        const int* __restrict__ uRevs, const int* __restrict__ iRevs,
                        const float* __restrict__ uEmb, const float* __restrict__ iEmb,
                        int* __restrict__ idxU, int* __restrict__ idxI,
                        float* __restrict__ MEAN, GKeys K) {
  int b = blockIdx.x, z = blockIdx.y, t = threadIdx.x;
  uint32_t ku0 = K.v[z * 4], ku1 = K.v[z * 4 + 1];
  uint32_t ki0 = K.v[z * 4 + 2], ki1 = K.v[z * 4 + 3];
  __shared__ float Is[30 * 301];
  __shared__ float Sc[900];
  __shared__ float us[30], vs[30];
  __shared__ int selU, selI;
  __shared__ int toksI_s[60], toksU_s[60];
  const float* Tb = Tall + (size_t)z * 1152000 + (size_t)b * 9000;
  const float* Ib = Iall + (size_t)z * 1152000 + (size_t)b * 9000;
  for (int e = t; e < 9000; e += 256) Is[(e / 300) * 301 + (e % 300)] = Ib[e];
  __syncthreads();
  for (int id = t; id < 900; id += 256) {
    int r = id / 30, c = id - r * 30;
    const float* tr = Tb + r * 300;
    const float* ic = Is + c * 301;
    float acc = 0.f;
    for (int k = 0; k < 300; ++k) acc = fmaf(tr[k], ic[k], acc);
    Sc[id] = acc;
  }
  __syncthreads();
  if (t < 30) {
    float m = -3.4e38f;
    for (int c = 0; c < 30; ++c) m = fmaxf(m, Sc[t * 30 + c]);
    us[t] = m + jax_gumbel32(ku0, ku1, (uint32_t)(b * 30 + t));
  } else if (t >= 64 && t < 94) {
    int s = t - 64;
    float m = -3.4e38f;
    for (int r = 0; r < 30; ++r) m = fmaxf(m, Sc[r * 30 + s]);
    vs[s] = m + jax_gumbel32(ki0, ki1, (uint32_t)(b * 30 + s));
  }
  __syncthreads();
  if (t == 0) {
    int best = 0; float bvv = us[0];
    for (int r = 1; r < 30; ++r) { if (us[r] > bvv) { bvv = us[r]; best = r; } }
    idxU[z * 128 + b] = best; selU = best;
  } else if (t == 1) {
    int best = 0; float bvv = vs[0];
    for (int s = 1; s < 30; ++s) { if (vs[s] > bvv) { bvv = vs[s]; best = s; } }
    idxI[z * 128 + b] = best; selI = best;
  }
  __syncthreads();
  if (t < 60) toksI_s[t] = iRevs[(b * 30 + selI) * 60 + t];
  else if (t >= 64 && t < 124) toksU_s[t - 64] = uRevs[(b * 30 + selU) * 60 + (t - 64)];
  __syncthreads();
  for (int dd = t; dd < 600; dd += 256) {
    int side = dd / 300;
    int d = dd - side * 300;
    const int* tk = side ? toksU_s : toksI_s;
    const float* em = side ? uEmb : iEmb;
    float acc = 0.f;
#pragma unroll
    for (int l0 = 0; l0 < 60; l0 += 10) {
      float v[10];
#pragma unroll
      for (int q = 0; q < 10; ++q)
        v[q] = em[(size_t)tk[l0 + q] * 300 + d];
#pragma unroll
      for (int q = 0; q < 10; ++q) acc += v[q];
    }
    MEAN[((size_t)(2 * z + side) * 128 + b) * 300 + d] = acc * (1.f / 60.f);
  }
}

// L6: per (b, side, p): scores = word rows . gvec; softmax; weighted sum.
__global__ __launch_bounds__(256)
void word_rep_kernel(const int* __restrict__ uRevs, const int* __restrict__ iRevs,
                     const float* __restrict__ uEmb, const float* __restrict__ iEmb,
                     const int* __restrict__ idxU, const int* __restrict__ idxI,
                     const float* __restrict__ GH, float* __restrict__ JNT) {
  int b = blockIdx.x, side = blockIdx.y, p = blockIdx.z;
  const int* revs = side ? iRevs : uRevs;
  const float* emb = side ? iEmb : uEmb;
  int idx = side ? idxI[p * 128 + b] : idxU[p * 128 + b];
  const float* gv = GH + ((size_t)(p * 2 + side) * 128 + b) * 300;
  __shared__ int toks[60];
  __shared__ float g_s[300];
  __shared__ float score[60];
  __shared__ float probs[64];
  int t = threadIdx.x;
  if (t < 60) toks[t] = revs[(b * 30 + idx) * 60 + t];
  for (int d = t; d < 300; d += 256) g_s[d] = gv[d];
  __syncthreads();
  int w = t >> 6, j = t & 63;
  for (int i = 0; i < 15; ++i) {
    int l = w * 15 + i;
    const float* er = emb + (size_t)toks[l] * 300;
    float partial = 0.f;
#pragma unroll
    for (int c = 0; c < 5; ++c) {
      int k = j + c * 64;
      if (k < 300) partial = fmaf(er[k], g_s[k], partial);
    }
#pragma unroll
    for (int m = 32; m >= 1; m >>= 1) partial += __shfl_xor(partial, m);
    if (j == 0) score[l] = partial;
  }
  __syncthreads();
  if (w == 0) {
    float s = (j < 60) ? score[j] : -3.4e38f;
    float m = s;
#pragma unroll
    for (int mm = 32; mm >= 1; mm >>= 1) m = fmaxf(m, __shfl_xor(m, mm));
    float e = (j < 60) ? expf(s - m) : 0.f;
    float sum = e;
#pragma unroll
    for (int mm = 32; mm >= 1; mm >>= 1) sum += __shfl_xor(sum, mm);
    if (j < 60) probs[j] = e / sum;
  }
  __syncthreads();
  float* outp = JNT + (size_t)b * 1800 + side * 900 + p * 300;
  for (int d = t; d < 300; d += 256) {
    float acc = 0.f;
    for (int l0 = 0; l0 < 60; l0 += 6) {
      float e0 = emb[(size_t)toks[l0 + 0] * 300 + d];
      float e1 = emb[(size_t)toks[l0 + 1] * 300 + d];
      float e2 = emb[(size_t)toks[l0 + 2] * 300 + d];
      float e3 = emb[(size_t)toks[l0 + 3] * 300 + d];
      float e4 = emb[(size_t)toks[l0 + 4] * 300 + d];
      float e5 = emb[(size_t)toks[l0 + 5] * 300 + d];
      acc = fmaf(probs[l0 + 0], e0, acc);
      acc = fmaf(probs[l0 + 1], e1, acc);
      acc = fmaf(probs[l0 + 2], e2, acc);
      acc = fmaf(probs[l0 + 3], e3, acc);
      acc = fmaf(probs[l0 + 4], e4, acc);
      acc = fmaf(probs[l0 + 5], e5, acc);
    }
    outp[d] = acc;
  }
}

// L7: factorization machine.
__global__ __launch_bounds__(64)
void fm_kernel(const float* __restrict__ JNT, const float* __restrict__ w0,
               const float* __restrict__ fw, const float* __restrict__ fv,
               float* __restrict__ out) {
  int b = blockIdx.x, lane = threadIdx.x;
  const float* x = JNT + (size_t)b * 1800;
  float lin = 0.f;
  float t1[10], t2[10];
#pragma unroll
  for (int k = 0; k < 10; ++k) { t1[k] = 0.f; t2[k] = 0.f; }
  for (int j = lane; j < 1800; j += 64) {
    float xv = x[j];
    lin = fmaf(fw[j], xv, lin);
    float xx = xv * xv;
#pragma unroll
    for (int k = 0; k < 10; ++k) {
      float v = fv[j * 10 + k];
      t1[k] = fmaf(xv, v, t1[k]);
      t2[k] = fmaf(xx, v * v, t2[k]);
    }
  }
#pragma unroll
  for (int m = 32; m >= 1; m >>= 1) {
    lin += __shfl_xor(lin, m);
#pragma unroll
    for (int k = 0; k < 10; ++k) {
      t1[k] += __shfl_xor(t1[k], m);
      t2[k] += __shfl_xor(t2[k], m);
    }
  }
  if (lane == 0) {
    float inter = 0.f;
#pragma unroll
    for (int k = 0; k < 10; ++k) inter += t1[k] * t1[k] - t2[k];
    out[b] = w0[0] + lin + 0.5f * inter;
  }
}

extern "C" void kernel_launch(void* const* d_in, const int* in_sizes, int n_in,
                              void* d_out, int out_size, void* d_ws, size_t ws_size,
                              hipStream_t stream) {
  (void)in_sizes; (void)n_in; (void)out_size;
  const int*   uRevs = (const int*)d_in[0];
  const int*   iRevs = (const int*)d_in[1];
  const float* uEmb  = (const float*)d_in[2];
  const float* iEmb  = (const float*)d_in[3];
  const float* g1w   = (const float*)d_in[4];
  const float* g1b   = (const float*)d_in[5];
  const float* g2w   = (const float*)d_in[6];
  const float* g2b   = (const float*)d_in[7];
  const float* Mr    = (const float*)d_in[8];
  const float* Wur   = (const float*)d_in[9];
  const float* bur   = (const float*)d_in[10];
  const float* Wir   = (const float*)d_in[11];
  const float* bir   = (const float*)d_in[12];
  const float* Mw    = (const float*)d_in[13];
  const float* Wuw   = (const float*)d_in[14];
  const float* buw   = (const float*)d_in[15];
  const float* Wiw   = (const float*)d_in[16];
  const float* biw   = (const float*)d_in[17];
  const float* fmw0  = (const float*)d_in[18];
  const float* fmw   = (const float*)d_in[19];
  const float* fmv   = (const float*)d_in[20];
  float* out = (float*)d_out;

  float* ws = (float*)d_ws;
  // Layout (floats), lifetime overlays:
  //   S @0 (2,304,000) L1..L2 ; TPall @0 (3,456,000) L3..L4
  //   REV @3,456,000 (2,304,000) L2..L3 ; MEAN @3,456,000 (230,400) L4..
  //   GH @3,686,400 ; JNT @3,916,800 ; idx @4,147,200 (768 int)
  //   IPall @5,760,000 (3,456,000) L3..L4
  //   A1 @9,216,000 ; Wp @9,486,000 ; KG @9,756,000 ; KGT @10,026,000 ;
  //   Bp @10,296,000 (900) ; CGH @10,296,900 (1800)
  const size_t NEED_BYTES = (size_t)10298700 * 4;
  if (ws_size < NEED_BYTES) return;

  float* S     = ws + 0;
  float* TPall = ws + 0;
  float* REV   = ws + 3456000;
  float* MEAN  = ws + 3456000;
  float* GH    = ws + 3686400;
  float* JNT   = ws + 3916800;
  int*   idxU  = (int*)(ws + 4147200);
  int*   idxI  = idxU + 384;
  float* IPall = ws + 5760000;
  float* A1    = ws + 9216000;
  float* Wp    = ws + 9486000;
  float* KG    = ws + 9756000;
  float* KGT   = ws + 10026000;
  float* Bp    = ws + 10296000;
  float* CGH   = ws + 10296900;

  // L0: weight precomputes (W', A1, bias chains)
  weights_kernel<<<dim3(153), dim3(256), 0, stream>>>(
      Wur, Mr, Mw, Wiw, Wuw, bur, buw, biw, Wp, A1, CGH, Bp);

  // L1: gather-sum (pure, minimal resources)
  gather_kernel<<<dim3(1920), dim3(320), 0, stream>>>(
      uRevs, iRevs, uEmb, iEmb, S);

  // L2: review gate + KG (+KGT)
  gate_kernel<<<dim3(675), dim3(256), 0, stream>>>(
      S, g1w, g1b, g2w, g2b, REV, Wuw, A1, KG, KGT);

  // L3: TP = REV_u @ W' + b' (NN) ; IP = REV_i @ Wir^T + bir (NT)
  {
    Ptr6 P;
    for (int z = 0; z < 3; ++z) {
      P.X[z] = REV;
      P.W[z] = Wp + (size_t)z * 90000;
      P.Bb[z] = Bp + z * 300;
      P.Y[z] = TPall + (size_t)z * 1152000;
      P.X[z + 3] = REV + (size_t)3840 * 300;
      P.W[z + 3] = Wir + (size_t)z * 90000;
      P.Bb[z + 3] = bir + z * 300;
      P.Y[z + 3] = IPall + (size_t)z * 1152000;
    }
    rev128_kernel<<<dim3(30, 5, 6), dim3(256), 0, stream>>>(P);
  }

  // L4: gumbel-argmax + fused MEAN
  {
    GKeys K;
    for (int p = 0; p < 3; ++p) {
      tf2x32(0u, 42u, 0u, (uint32_t)(2 * p),     &K.v[p * 4],     &K.v[p * 4 + 1]);
      tf2x32(0u, 42u, 0u, (uint32_t)(2 * p + 1), &K.v[p * 4 + 2], &K.v[p * 4 + 3]);
    }
    argmax_mean_kernel<<<dim3(128, 3), dim3(256), 0, stream>>>(
        TPall, IPall, uRevs, iRevs, uEmb, iEmb, idxU, idxI, MEAN, K);
  }

  // L5: GH[2p] = MEAN_i @ KG^T + c_g ; GH[2p+1] = MEAN_u @ KG + c_h
  {
    Ptr6 P;
    for (int zz = 0; zz < 6; ++zz) {
      int p = zz >> 1;
      P.X[zz] = MEAN + (size_t)zz * 38400;
      P.W[zz] = (zz & 1) ? KG + (size_t)p * 90000 : KGT + (size_t)p * 90000;
      P.Bb[zz] = CGH + (size_t)zz * 300;
      P.Y[zz] = GH + (size_t)zz * 38400;
    }
    nn6_kernel<true><<<dim3(2, 5, 6), dim3(256), 0, stream>>>(P, 128);
  }

  // L6: word-level softmax representations
  word_rep_kernel<<<dim3(128, 2, 3), dim3(256), 0, stream>>>(
      uRevs, iRevs, uEmb, iEmb, idxU, idxI, GH, JNT);

  // L7: factorization machine
  fm_kernel<<<dim3(128), dim3(64), 0, stream>>>(JNT, fmw0, fmw, fmv, out);
}